// Round 2
// baseline (8835.842 us; speedup 1.0000x reference)
//
#include <hip/hip_runtime.h>
#include <hip/hip_bf16.h>
#include <math.h>

#define NCIRC 40000
#define NMI   15000
#define NDIS  8000
#define NTOT  (NCIRC + NMI + NDIS)

typedef __hip_bfloat16 bf16;

static __device__ __forceinline__ float b2f(bf16 x){ return __bfloat162float(x); }
static __device__ __forceinline__ float ldx(const void* p, size_t i, int f32){
    return f32 ? ((const float*)p)[i] : __bfloat162float(((const bf16*)p)[i]);
}
static inline unsigned cdiv(long long a, long long b){ return (unsigned)((a + b - 1) / b); }

// ---------- dtype detection: fp32-as-bf16 shows huge exponents in ~44% of samples ----------
__global__ void detect_dtype(const unsigned short* __restrict__ u, int* __restrict__ flag){
    int bad = 0;
    for (int i = threadIdx.x; i < 4096; i += 256){
        int e = (u[i] >> 7) & 0xFF;
        if (e >= 0x90) bad = 1;
    }
    if (bad) atomicOr(flag, 1);
}

// ---------- weight folding: wa[f*4+h] = sum_c W1[r][f][h*64+c]*a1[r][h][c] ----------
__global__ void compute_wa1(const void* __restrict__ W1, const void* __restrict__ as1,
                            const void* __restrict__ ad1, int r, const int* __restrict__ flag,
                            float* __restrict__ wa_s, float* __restrict__ wa_d){
    int f32 = *flag;
    int t = threadIdx.x;            // 0..511 -> f*4+h
    int f = t >> 2, h = t & 3;
    size_t wb = (size_t)r*128*256 + (size_t)f*256 + h*64;
    size_t ab = (size_t)r*256 + h*64;
    float ss = 0.f, sd = 0.f;
    for (int c = 0; c < 64; c++){
        float w = ldx(W1, wb + c, f32);
        ss += w * ldx(as1, ab + c, f32);
        sd += w * ldx(ad1, ab + c, f32);
    }
    wa_s[t] = ss; wa_d[t] = sd;
}

__global__ void compute_wa2(const void* __restrict__ W2, const void* __restrict__ as2,
                            const void* __restrict__ ad2, int r, const int* __restrict__ flag,
                            float* __restrict__ wa_s, float* __restrict__ wa_d){
    int f32 = *flag;
    int f = threadIdx.x;            // 0..255
    size_t wb = (size_t)r*256*64 + (size_t)f*64;
    float ss = 0.f, sd = 0.f;
    for (int c = 0; c < 64; c++){
        float w = ldx(W2, wb + c, f32);
        ss += w * ldx(as2, (size_t)r*64 + c, f32);
        sd += w * ldx(ad2, (size_t)r*64 + c, f32);
    }
    wa_s[f] = ss; wa_d[f] = sd;
}

// ---------- attention logits ----------
__global__ void compute_al1(const void* __restrict__ X, const int* __restrict__ flag,
                            const float* __restrict__ wa, float* __restrict__ al, int N){
    int f32 = *flag;
    int i = blockIdx.x * blockDim.x + threadIdx.x;
    if (i >= N*4) return;
    int n = i >> 2, h = i & 3;
    size_t xb = (size_t)n*128;
    float s = 0.f;
    for (int f = 0; f < 128; f++) s += ldx(X, xb + f, f32) * wa[f*4 + h];
    al[i] = s;
}

__global__ void compute_al2(const float* __restrict__ X, const float* __restrict__ wa,
                            float* __restrict__ al, int N){
    int n = blockIdx.x * blockDim.x + threadIdx.x;
    if (n >= N) return;
    const float* xr = X + (size_t)n*256;
    float s = 0.f;
    for (int f = 0; f < 256; f++) s += xr[f] * wa[f];
    al[n] = s;
}

// ---------- GEMM: C[M,N](bf16) = A[M,K] @ B[K,N]; bOff = element offset into B ----------
// mode: 0 = bf16, 1 = f32, 2 = per-flag
__global__ void gemm_ad(const void* __restrict__ A, int amode,
                        const void* __restrict__ B, int bmode, size_t bOff,
                        const int* __restrict__ flag, bf16* __restrict__ C,
                        int M, int N, int K){
    int fl = *flag;
    int af32 = (amode == 2) ? fl : amode;
    int bf32 = (bmode == 2) ? fl : bmode;
    __shared__ float As[16][66];
    __shared__ float Bs[16][66];
    int tid = threadIdx.x;
    int m0 = blockIdx.y * 64, n0 = blockIdx.x * 64;
    int tm = (tid >> 4) << 2, tn = (tid & 15) << 2;
    float acc[4][4] = {};
    for (int k0 = 0; k0 < K; k0 += 16){
        {
            int mi = tid >> 2, ki = (tid & 3) << 2;
            int row = m0 + mi;
            if (row < M){
                size_t ab = (size_t)row*K + k0 + ki;
                #pragma unroll
                for (int j = 0; j < 4; j++) As[ki + j][mi] = ldx(A, ab + j, af32);
            } else {
                #pragma unroll
                for (int j = 0; j < 4; j++) As[ki + j][mi] = 0.f;
            }
        }
        {
            int ki = tid >> 4, ni = (tid & 15) << 2;
            size_t bb = bOff + (size_t)(k0 + ki)*N + n0 + ni;
            #pragma unroll
            for (int j = 0; j < 4; j++) Bs[ki][ni + j] = ldx(B, bb + j, bf32);
        }
        __syncthreads();
        #pragma unroll
        for (int kk = 0; kk < 16; kk++){
            float a[4], b[4];
            #pragma unroll
            for (int i = 0; i < 4; i++) a[i] = As[kk][tm + i];
            #pragma unroll
            for (int j = 0; j < 4; j++) b[j] = Bs[kk][tn + j];
            #pragma unroll
            for (int i = 0; i < 4; i++)
                #pragma unroll
                for (int j = 0; j < 4; j++)
                    acc[i][j] += a[i] * b[j];
        }
        __syncthreads();
    }
    #pragma unroll
    for (int i = 0; i < 4; i++){
        int row = m0 + tm + i;
        if (row < M){
            bf16* cp = C + (size_t)row*N + n0 + tn;
            #pragma unroll
            for (int j = 0; j < 4; j++) cp[j] = __float2bfloat16(acc[i][j]);
        }
    }
}

// ---------- edge kernels (max-pass dropped: |logits| small, exp(le) safe; identical math) ----------
template<int H>
__global__ void edge_den(const int* __restrict__ src, const int* __restrict__ dst,
                         const float* __restrict__ als, const float* __restrict__ ald,
                         float* __restrict__ den, int E){
    int e = blockIdx.x * blockDim.x + threadIdx.x;
    if (e >= E) return;
    int s = src[e], d = dst[e];
    #pragma unroll
    for (int h = 0; h < H; h++){
        float a = als[s*H + h] + ald[d*H + h];
        float le = a > 0.f ? a : 0.2f * a;
        unsafeAtomicAdd(&den[d*H + h], __expf(le));
    }
}

__global__ void edge_scatter256(const int* __restrict__ src, const int* __restrict__ dst,
                                const float* __restrict__ als, const float* __restrict__ ald,
                                const float* __restrict__ den, const bf16* __restrict__ HS,
                                float* __restrict__ acc, int E){
    int t = blockIdx.x * blockDim.x + threadIdx.x;
    int e = t >> 6;
    if (e >= E) return;
    int lane = t & 63;
    int s = src[e], d = dst[e];
    int c0 = lane << 2;
    int h = c0 >> 6;
    float a = als[s*4 + h] + ald[d*4 + h];
    float le = a > 0.f ? a : 0.2f * a;
    float alpha = __expf(le) / (den[d*4 + h] + 1e-16f);
    const bf16* hp = HS + (size_t)s*256 + c0;
    float* ap = acc + (size_t)d*256 + c0;
    unsafeAtomicAdd(ap + 0, alpha * b2f(hp[0]));
    unsafeAtomicAdd(ap + 1, alpha * b2f(hp[1]));
    unsafeAtomicAdd(ap + 2, alpha * b2f(hp[2]));
    unsafeAtomicAdd(ap + 3, alpha * b2f(hp[3]));
}

__global__ void edge_scatter64(const int* __restrict__ src, const int* __restrict__ dst,
                               const float* __restrict__ als, const float* __restrict__ ald,
                               const float* __restrict__ den, const bf16* __restrict__ HS,
                               float* __restrict__ acc, int E){
    int t = blockIdx.x * blockDim.x + threadIdx.x;
    int e = t >> 6;
    if (e >= E) return;
    int lane = t & 63;
    int s = src[e], d = dst[e];
    float a = als[s] + ald[d];
    float le = a > 0.f ? a : 0.2f * a;
    float alpha = __expf(le) / (den[d] + 1e-16f);
    unsafeAtomicAdd(acc + (size_t)d*64 + lane, alpha * b2f(HS[(size_t)s*64 + lane]));
}

// ---------- epilogues ----------
__global__ void elu_bias(float* __restrict__ acc, const void* __restrict__ b1,
                         const int* __restrict__ flag, int ra, int rb, int N){
    int f32 = *flag;
    int i = blockIdx.x * blockDim.x + threadIdx.x;
    if (i >= N*256) return;
    int c = i & 255;
    float v = acc[i] * 0.5f + 0.5f * (ldx(b1, ra*256 + c, f32) + ldx(b1, rb*256 + c, f32));
    acc[i] = v > 0.f ? v : (__expf(v) - 1.0f);
}

// outOff = global element offset of this type's first node
__global__ void finalize(const float* __restrict__ acc, const void* __restrict__ b2,
                         const int* __restrict__ flag, int ra, int rb,
                         void* __restrict__ out, size_t outOff, int N){
    int f32 = *flag;
    int t = blockIdx.x * blockDim.x + threadIdx.x;
    int n = t >> 6;
    if (n >= N) return;
    int lane = t & 63;
    float v = acc[(size_t)n*64 + lane] * 0.5f
            + 0.5f * (ldx(b2, ra*64 + lane, f32) + ldx(b2, rb*64 + lane, f32));
    float ss = v * v;
    #pragma unroll
    for (int mk = 32; mk > 0; mk >>= 1) ss += __shfl_xor(ss, mk, 64);
    float nrm = sqrtf(ss);
    nrm = nrm > 1e-12f ? nrm : 1e-12f;
    float r = v / nrm;
    size_t idx = outOff + (size_t)n*64 + lane;
    if (f32) ((float*)out)[idx] = r;
    else     ((bf16*)out)[idx] = __float2bfloat16(r);
}

// ---------- host ----------
extern "C" void kernel_launch(void* const* d_in, const int* in_sizes, int n_in,
                              void* d_out, int out_size, void* d_ws, size_t ws_size,
                              hipStream_t stream){
    const void* x[3] = {d_in[0], d_in[1], d_in[2]};
    const int Nt[3] = {NCIRC, NMI, NDIS};
    const int* ep[6]; int Ecnt[6];
    for (int r = 0; r < 6; r++){ ep[r] = (const int*)d_in[3 + r]; Ecnt[r] = in_sizes[3 + r] / 2; }
    const void* W1  = d_in[9];
    const void* as1 = d_in[10];
    const void* ad1 = d_in[11];
    const void* b1  = d_in[12];
    const void* W2  = d_in[13];
    const void* as2 = d_in[14];
    const void* ad2 = d_in[15];
    const void* b2  = d_in[16];

    const int rs[6] = {0, 1, 0, 1, 2, 2};
    const int rd[6] = {1, 2, 2, 0, 1, 0};
    const int relA[3] = {3, 0, 1};
    const int relB[3] = {5, 4, 2};
    const int accRow[3] = {0, NCIRC, NCIRC + NMI};

    // workspace (88.4 MB)
    float* ws   = (float*)d_ws;
    int*   FLAG = (int*)ws;
    float* R1   = ws + 16;                 // 5.5M floats: L1 HS1 bf16 / L2 ACC2 fp32 + HS2 bf16
    float* ALS  = R1 + 5500000;
    float* ALD  = ALS + 160000;
    float* DEN  = ALD + 160000;
    float* ACC1 = DEN + 160000;            // 16.128M floats (becomes X2)
    float* WAs  = ACC1 + (size_t)NTOT*256;
    float* WAd  = WAs + 512;
    bf16*  HS1  = (bf16*)R1;
    float* ACC2 = R1;
    bf16*  HS2  = (bf16*)(R1 + 4032000);

    hipMemsetAsync(FLAG, 0, sizeof(int), stream);
    detect_dtype<<<1, 256, 0, stream>>>((const unsigned short*)d_in[0], FLAG);

    // ===== layer 1 =====
    hipMemsetAsync(ACC1, 0, (size_t)NTOT*256*sizeof(float), stream);
    for (int r = 0; r < 6; r++){
        int s = rs[r], d = rd[r];
        int Ns = Nt[s], Nd = Nt[d], E = Ecnt[r];
        const int* srcp = ep[r];
        const int* dstp = ep[r] + E;

        compute_wa1<<<1, 512, 0, stream>>>(W1, as1, ad1, r, FLAG, WAs, WAd);
        compute_al1<<<cdiv((long long)Ns*4, 256), 256, 0, stream>>>(x[s], FLAG, WAs, ALS, Ns);
        compute_al1<<<cdiv((long long)Nd*4, 256), 256, 0, stream>>>(x[d], FLAG, WAd, ALD, Nd);
        gemm_ad<<<dim3(4, cdiv(Ns, 64)), 256, 0, stream>>>(
            x[s], 2, W1, 2, (size_t)r*128*256, FLAG, HS1, Ns, 256, 128);
        hipMemsetAsync(DEN, 0, (size_t)Nd*4*sizeof(float), stream);
        edge_den<4><<<cdiv(E, 256), 256, 0, stream>>>(srcp, dstp, ALS, ALD, DEN, E);
        edge_scatter256<<<cdiv((long long)E*64, 256), 256, 0, stream>>>(
            srcp, dstp, ALS, ALD, DEN, HS1, ACC1 + (size_t)accRow[d]*256, E);
    }
    for (int t = 0; t < 3; t++){
        elu_bias<<<cdiv((long long)Nt[t]*256, 256), 256, 0, stream>>>(
            ACC1 + (size_t)accRow[t]*256, b1, FLAG, relA[t], relB[t], Nt[t]);
    }

    // ===== layer 2 =====
    hipMemsetAsync(ACC2, 0, (size_t)NTOT*64*sizeof(float), stream);
    for (int r = 0; r < 6; r++){
        int s = rs[r], d = rd[r];
        int Ns = Nt[s], Nd = Nt[d], E = Ecnt[r];
        const int* srcp = ep[r];
        const int* dstp = ep[r] + E;
        const float* X2s = ACC1 + (size_t)accRow[s]*256;
        const float* X2d = ACC1 + (size_t)accRow[d]*256;

        compute_wa2<<<1, 256, 0, stream>>>(W2, as2, ad2, r, FLAG, WAs, WAd);
        compute_al2<<<cdiv(Ns, 256), 256, 0, stream>>>(X2s, WAs, ALS, Ns);
        compute_al2<<<cdiv(Nd, 256), 256, 0, stream>>>(X2d, WAd, ALD, Nd);
        gemm_ad<<<dim3(1, cdiv(Ns, 64)), 256, 0, stream>>>(
            X2s, 1, W2, 2, (size_t)r*256*64, FLAG, HS2, Ns, 64, 256);
        hipMemsetAsync(DEN, 0, (size_t)Nd*sizeof(float), stream);
        edge_den<1><<<cdiv(E, 256), 256, 0, stream>>>(srcp, dstp, ALS, ALD, DEN, E);
        edge_scatter64<<<cdiv((long long)E*64, 256), 256, 0, stream>>>(
            srcp, dstp, ALS, ALD, DEN, HS2, ACC2 + (size_t)accRow[d]*64, E);
    }

    // ===== finalize =====
    size_t oOff[3] = {0, (size_t)NCIRC*64, (size_t)(NCIRC + NMI)*64};
    for (int t = 0; t < 3; t++){
        finalize<<<cdiv((long long)Nt[t]*64, 256), 256, 0, stream>>>(
            ACC2 + (size_t)accRow[t]*64, b2, FLAG, relA[t], relB[t], d_out, oOff[t], Nt[t]);
    }
}

// Round 3
// 2738.938 us; speedup vs baseline: 3.2260x; 3.2260x over previous
//
#include <hip/hip_runtime.h>
#include <hip/hip_bf16.h>
#include <math.h>

#define NCIRC 40000
#define NMI   15000
#define NDIS  8000
#define NTOT  (NCIRC + NMI + NDIS)

typedef __hip_bfloat16 bf16;

static __device__ __forceinline__ float b2f(bf16 x){ return __bfloat162float(x); }
static __device__ __forceinline__ float us2f(unsigned short u){ return __uint_as_float(((unsigned)u) << 16); }
static __device__ __forceinline__ float ldx(const void* p, size_t i, int f32){
    return f32 ? ((const float*)p)[i] : __bfloat162float(((const bf16*)p)[i]);
}
static inline unsigned cdiv(long long a, long long b){ return (unsigned)((a + b - 1) / b); }

// ---------- dtype detection ----------
__global__ void detect_dtype(const unsigned short* __restrict__ u, int* __restrict__ flag){
    int bad = 0;
    for (int i = threadIdx.x; i < 4096; i += 256){
        int e = (u[i] >> 7) & 0xFF;
        if (e >= 0x90) bad = 1;
    }
    if (bad) atomicOr(flag, 1);
}

// ---------- CSR build ----------
__global__ void csr_count(const int* __restrict__ dst, int E, int* __restrict__ cnt){
    int e = blockIdx.x * blockDim.x + threadIdx.x;
    if (e < E) atomicAdd(&cnt[dst[e]], 1);
}

// exclusive prefix: off[0]=0, off[i+1]=sum cnt[0..i]; single block 1024 threads
__global__ void csr_scan(const int* __restrict__ cnt, int* __restrict__ off, int N){
    __shared__ int s[1024];
    __shared__ int base;
    int tid = threadIdx.x;
    if (tid == 0) base = 0;
    __syncthreads();
    for (int c0 = 0; c0 < N; c0 += 1024){
        int i = c0 + tid;
        s[tid] = (i < N) ? cnt[i] : 0;
        __syncthreads();
        for (int d = 1; d < 1024; d <<= 1){
            int t2 = (tid >= d) ? s[tid - d] : 0;
            __syncthreads();
            s[tid] += t2;
            __syncthreads();
        }
        if (i < N) off[i + 1] = base + s[tid];
        __syncthreads();
        if (tid == 0) base += s[1023];
        __syncthreads();
    }
    if (tid == 0) off[0] = 0;
}

__global__ void csr_fill(const int* __restrict__ dst, int E, const int* __restrict__ off,
                         int* __restrict__ pos, int* __restrict__ eord){
    int e = blockIdx.x * blockDim.x + threadIdx.x;
    if (e >= E) return;
    int d = dst[e];
    int p = atomicAdd(&pos[d], 1);
    eord[off[d] + p] = e;
}

// ---------- weight folding ----------
__global__ void compute_wa1(const void* __restrict__ W1, const void* __restrict__ as1,
                            const void* __restrict__ ad1, int r, const int* __restrict__ flag,
                            float* __restrict__ wa_s, float* __restrict__ wa_d){
    int f32 = *flag;
    int t = threadIdx.x;            // 0..511 -> f*4+h
    int f = t >> 2, h = t & 3;
    size_t wb = (size_t)r*128*256 + (size_t)f*256 + h*64;
    size_t ab = (size_t)r*256 + h*64;
    float ss = 0.f, sd = 0.f;
    for (int c = 0; c < 64; c++){
        float w = ldx(W1, wb + c, f32);
        ss += w * ldx(as1, ab + c, f32);
        sd += w * ldx(ad1, ab + c, f32);
    }
    wa_s[t] = ss; wa_d[t] = sd;
}

__global__ void compute_wa2(const void* __restrict__ W2, const void* __restrict__ as2,
                            const void* __restrict__ ad2, int r, const int* __restrict__ flag,
                            float* __restrict__ wa_s, float* __restrict__ wa_d){
    int f32 = *flag;
    int f = threadIdx.x;            // 0..255
    size_t wb = (size_t)r*256*64 + (size_t)f*64;
    float ss = 0.f, sd = 0.f;
    for (int c = 0; c < 64; c++){
        float w = ldx(W2, wb + c, f32);
        ss += w * ldx(as2, (size_t)r*64 + c, f32);
        sd += w * ldx(ad2, (size_t)r*64 + c, f32);
    }
    wa_s[f] = ss; wa_d[f] = sd;
}

// ---------- attention logits ----------
__global__ void compute_al1(const void* __restrict__ X, const int* __restrict__ flag,
                            const float* __restrict__ wa, float* __restrict__ al, int N){
    int f32 = *flag;
    int i = blockIdx.x * blockDim.x + threadIdx.x;
    if (i >= N*4) return;
    int n = i >> 2, h = i & 3;
    size_t xb = (size_t)n*128;
    float s = 0.f;
    for (int f = 0; f < 128; f++) s += ldx(X, xb + f, f32) * wa[f*4 + h];
    al[i] = s;
}

__global__ void compute_al2(const float* __restrict__ X, const float* __restrict__ wa,
                            float* __restrict__ al, int N){
    int n = blockIdx.x * blockDim.x + threadIdx.x;
    if (n >= N) return;
    const float* xr = X + (size_t)n*256;
    float s = 0.f;
    for (int f = 0; f < 256; f++) s += xr[f] * wa[f];
    al[n] = s;
}

// ---------- GEMM: C[M,N](bf16) = A[M,K] @ B[K,N]; bOff = element offset ----------
// mode: 0 = bf16, 1 = f32, 2 = per-flag
__global__ void gemm_ad(const void* __restrict__ A, int amode,
                        const void* __restrict__ B, int bmode, size_t bOff,
                        const int* __restrict__ flag, bf16* __restrict__ C,
                        int M, int N, int K){
    int fl = *flag;
    int af32 = (amode == 2) ? fl : amode;
    int bf32 = (bmode == 2) ? fl : bmode;
    __shared__ float As[16][66];
    __shared__ float Bs[16][66];
    int tid = threadIdx.x;
    int m0 = blockIdx.y * 64, n0 = blockIdx.x * 64;
    int tm = (tid >> 4) << 2, tn = (tid & 15) << 2;
    float acc[4][4] = {};
    for (int k0 = 0; k0 < K; k0 += 16){
        {
            int mi = tid >> 2, ki = (tid & 3) << 2;
            int row = m0 + mi;
            if (row < M){
                size_t ab = (size_t)row*K + k0 + ki;
                #pragma unroll
                for (int j = 0; j < 4; j++) As[ki + j][mi] = ldx(A, ab + j, af32);
            } else {
                #pragma unroll
                for (int j = 0; j < 4; j++) As[ki + j][mi] = 0.f;
            }
        }
        {
            int ki = tid >> 4, ni = (tid & 15) << 2;
            size_t bb = bOff + (size_t)(k0 + ki)*N + n0 + ni;
            #pragma unroll
            for (int j = 0; j < 4; j++) Bs[ki][ni + j] = ldx(B, bb + j, bf32);
        }
        __syncthreads();
        #pragma unroll
        for (int kk = 0; kk < 16; kk++){
            float a[4], b[4];
            #pragma unroll
            for (int i = 0; i < 4; i++) a[i] = As[kk][tm + i];
            #pragma unroll
            for (int j = 0; j < 4; j++) b[j] = Bs[kk][tn + j];
            #pragma unroll
            for (int i = 0; i < 4; i++)
                #pragma unroll
                for (int j = 0; j < 4; j++)
                    acc[i][j] += a[i] * b[j];
        }
        __syncthreads();
    }
    #pragma unroll
    for (int i = 0; i < 4; i++){
        int row = m0 + tm + i;
        if (row < M){
            bf16* cp = C + (size_t)row*N + n0 + tn;
            #pragma unroll
            for (int j = 0; j < 4; j++) cp[j] = __float2bfloat16(acc[i][j]);
        }
    }
}

// ---------- gather-style GAT aggregation (one wave per dst node) ----------
// pass 1: den = sum exp(leaky(al_s+al_d)) over incoming edges (every lane sees every
// edge, so each lane independently accumulates the den for its head -> no reduce).
// pass 2: acc += alpha * HS[src]. Write row once (add=0: store, add=1: +=).
__global__ void gat_gather256(const int* __restrict__ src, const int* __restrict__ eord,
                              const int* __restrict__ off, const float* __restrict__ als,
                              const float* __restrict__ ald, const bf16* __restrict__ HS,
                              float* __restrict__ acc, int add, int Nd){
    int t = blockIdx.x * blockDim.x + threadIdx.x;
    int w = t >> 6;
    if (w >= Nd) return;
    int lane = t & 63;
    int h = lane >> 4;              // 4 heads, 16 lanes each (lane*4 channels / 64)
    float aldv = ald[w*4 + h];
    int beg = off[w], end = off[w+1];
    float den = 1e-16f;
    for (int i = beg; i < end; i++){
        int s = src[eord[i]];
        float a = als[s*4 + h] + aldv;
        den += __expf(a > 0.f ? a : 0.2f * a);
    }
    float inv = 1.0f / den;
    float a0 = 0.f, a1 = 0.f, a2 = 0.f, a3 = 0.f;
    const unsigned short* Hu = (const unsigned short*)HS;
    for (int i = beg; i < end; i++){
        int s = src[eord[i]];
        float a = als[s*4 + h] + aldv;
        float alpha = __expf(a > 0.f ? a : 0.2f * a) * inv;
        ushort4 hv = *(const ushort4*)(Hu + (size_t)s*256 + lane*4);
        a0 += alpha * us2f(hv.x);
        a1 += alpha * us2f(hv.y);
        a2 += alpha * us2f(hv.z);
        a3 += alpha * us2f(hv.w);
    }
    float* ap = acc + (size_t)w*256 + lane*4;
    if (add){ ap[0] += a0; ap[1] += a1; ap[2] += a2; ap[3] += a3; }
    else    { ap[0]  = a0; ap[1]  = a1; ap[2]  = a2; ap[3]  = a3; }
}

__global__ void gat_gather64(const int* __restrict__ src, const int* __restrict__ eord,
                             const int* __restrict__ off, const float* __restrict__ als,
                             const float* __restrict__ ald, const bf16* __restrict__ HS,
                             float* __restrict__ acc, int add, int Nd){
    int t = blockIdx.x * blockDim.x + threadIdx.x;
    int w = t >> 6;
    if (w >= Nd) return;
    int lane = t & 63;
    float aldv = ald[w];
    int beg = off[w], end = off[w+1];
    float den = 1e-16f;
    for (int i = beg; i < end; i++){
        int s = src[eord[i]];
        float a = als[s] + aldv;
        den += __expf(a > 0.f ? a : 0.2f * a);
    }
    float inv = 1.0f / den;
    float a0 = 0.f;
    for (int i = beg; i < end; i++){
        int s = src[eord[i]];
        float a = als[s] + aldv;
        float alpha = __expf(a > 0.f ? a : 0.2f * a) * inv;
        a0 += alpha * b2f(HS[(size_t)s*64 + lane]);
    }
    float* ap = acc + (size_t)w*64 + lane;
    if (add) *ap += a0; else *ap = a0;
}

// ---------- epilogues ----------
__global__ void elu_bias(float* __restrict__ acc, const void* __restrict__ b1,
                         const int* __restrict__ flag, int ra, int rb, int N){
    int f32 = *flag;
    int i = blockIdx.x * blockDim.x + threadIdx.x;
    if (i >= N*256) return;
    int c = i & 255;
    float v = acc[i] * 0.5f + 0.5f * (ldx(b1, ra*256 + c, f32) + ldx(b1, rb*256 + c, f32));
    acc[i] = v > 0.f ? v : (__expf(v) - 1.0f);
}

__global__ void finalize(const float* __restrict__ acc, const void* __restrict__ b2,
                         const int* __restrict__ flag, int ra, int rb,
                         void* __restrict__ out, size_t outOff, int N){
    int f32 = *flag;
    int t = blockIdx.x * blockDim.x + threadIdx.x;
    int n = t >> 6;
    if (n >= N) return;
    int lane = t & 63;
    float v = acc[(size_t)n*64 + lane] * 0.5f
            + 0.5f * (ldx(b2, ra*64 + lane, f32) + ldx(b2, rb*64 + lane, f32));
    float ss = v * v;
    #pragma unroll
    for (int mk = 32; mk > 0; mk >>= 1) ss += __shfl_xor(ss, mk, 64);
    float nrm = sqrtf(ss);
    nrm = nrm > 1e-12f ? nrm : 1e-12f;
    float r = v / nrm;
    size_t idx = outOff + (size_t)n*64 + lane;
    if (f32) ((float*)out)[idx] = r;
    else     ((bf16*)out)[idx] = __float2bfloat16(r);
}

// ---------- host ----------
extern "C" void kernel_launch(void* const* d_in, const int* in_sizes, int n_in,
                              void* d_out, int out_size, void* d_ws, size_t ws_size,
                              hipStream_t stream){
    const void* x[3] = {d_in[0], d_in[1], d_in[2]};
    const int Nt[3] = {NCIRC, NMI, NDIS};
    const int* ep[6]; int Ecnt[6];
    for (int r = 0; r < 6; r++){ ep[r] = (const int*)d_in[3 + r]; Ecnt[r] = in_sizes[3 + r] / 2; }
    const void* W1  = d_in[9];
    const void* as1 = d_in[10];
    const void* ad1 = d_in[11];
    const void* b1  = d_in[12];
    const void* W2  = d_in[13];
    const void* as2 = d_in[14];
    const void* ad2 = d_in[15];
    const void* b2  = d_in[16];

    const int rs[6] = {0, 1, 0, 1, 2, 2};
    const int rd[6] = {1, 2, 2, 0, 1, 0};
    const int relA[3] = {3, 0, 1};
    const int relB[3] = {5, 4, 2};
    const int addF[6] = {0, 0, 1, 0, 1, 1};   // second relation landing on a type adds
    const int accRow[3] = {0, NCIRC, NCIRC + NMI};

    // ---- workspace layout (~95.7 MB) ----
    float* ws   = (float*)d_ws;
    int*   FLAG = (int*)ws;                          // [16]
    float* R1   = ws + 16;                           // [5,500,000]  HS1 bf16 | ACC2 f32 + HS2 bf16
    float* ALS  = R1 + 5500000;                      // [160,000]
    float* ALD  = ALS + 160000;                      // [160,000]
    float* ACC1 = ALD + 160000;                      // [16,128,000] (becomes X2)
    float* WAs  = ACC1 + (size_t)NTOT*256;           // [512]
    float* WAd  = WAs + 512;                         // [512]
    int*   CNT  = (int*)(WAd + 512);                 // [40,064]
    int*   OFF  = CNT + 40064;                       // [6 * 40,064]
    int*   EORD = OFF + 6*40064;                     // [2,000,000]
    bf16*  HS1  = (bf16*)R1;
    float* ACC2 = R1;
    bf16*  HS2  = (bf16*)(R1 + 4032000);

    hipMemsetAsync(FLAG, 0, sizeof(int), stream);
    detect_dtype<<<1, 256, 0, stream>>>((const unsigned short*)d_in[0], FLAG);

    // ---- build CSR (group edges by dst) for all 6 relations ----
    size_t eOff[6]; size_t acc_e = 0;
    for (int r = 0; r < 6; r++){ eOff[r] = acc_e; acc_e += Ecnt[r]; }
    for (int r = 0; r < 6; r++){
        int Nd = Nt[rd[r]], E = Ecnt[r];
        const int* dstp = ep[r] + E;
        int* offR = OFF + r*40064;
        hipMemsetAsync(CNT, 0, (size_t)Nd*sizeof(int), stream);
        csr_count<<<cdiv(E, 256), 256, 0, stream>>>(dstp, E, CNT);
        csr_scan<<<1, 1024, 0, stream>>>(CNT, offR, Nd);
        hipMemsetAsync(CNT, 0, (size_t)Nd*sizeof(int), stream);
        csr_fill<<<cdiv(E, 256), 256, 0, stream>>>(dstp, E, offR, CNT, EORD + eOff[r]);
    }

    // ===== layer 1 =====
    for (int r = 0; r < 6; r++){
        int s = rs[r], d = rd[r];
        int Ns = Nt[s], Nd = Nt[d], E = Ecnt[r];
        const int* srcp = ep[r];

        compute_wa1<<<1, 512, 0, stream>>>(W1, as1, ad1, r, FLAG, WAs, WAd);
        compute_al1<<<cdiv((long long)Ns*4, 256), 256, 0, stream>>>(x[s], FLAG, WAs, ALS, Ns);
        compute_al1<<<cdiv((long long)Nd*4, 256), 256, 0, stream>>>(x[d], FLAG, WAd, ALD, Nd);
        gemm_ad<<<dim3(4, cdiv(Ns, 64)), 256, 0, stream>>>(
            x[s], 2, W1, 2, (size_t)r*128*256, FLAG, HS1, Ns, 256, 128);
        gat_gather256<<<cdiv((long long)Nd*64, 256), 256, 0, stream>>>(
            srcp, EORD + eOff[r], OFF + r*40064, ALS, ALD, HS1,
            ACC1 + (size_t)accRow[d]*256, addF[r], Nd);
        (void)E;
    }
    for (int t = 0; t < 3; t++){
        elu_bias<<<cdiv((long long)Nt[t]*256, 256), 256, 0, stream>>>(
            ACC1 + (size_t)accRow[t]*256, b1, FLAG, relA[t], relB[t], Nt[t]);
    }

    // ===== layer 2 =====
    for (int r = 0; r < 6; r++){
        int s = rs[r], d = rd[r];
        int Ns = Nt[s], Nd = Nt[d];
        const int* srcp = ep[r];
        const float* X2s = ACC1 + (size_t)accRow[s]*256;
        const float* X2d = ACC1 + (size_t)accRow[d]*256;

        compute_wa2<<<1, 256, 0, stream>>>(W2, as2, ad2, r, FLAG, WAs, WAd);
        compute_al2<<<cdiv(Ns, 256), 256, 0, stream>>>(X2s, WAs, ALS, Ns);
        compute_al2<<<cdiv(Nd, 256), 256, 0, stream>>>(X2d, WAd, ALD, Nd);
        gemm_ad<<<dim3(1, cdiv(Ns, 64)), 256, 0, stream>>>(
            X2s, 1, W2, 2, (size_t)r*256*64, FLAG, HS2, Ns, 64, 256);
        gat_gather64<<<cdiv((long long)Nd*64, 256), 256, 0, stream>>>(
            srcp, EORD + eOff[r], OFF + r*40064, ALS, ALD, HS2,
            ACC2 + (size_t)accRow[d]*64, addF[r], Nd);
    }

    // ===== finalize =====
    size_t oOff[3] = {0, (size_t)NCIRC*64, (size_t)(NCIRC + NMI)*64};
    for (int t = 0; t < 3; t++){
        finalize<<<cdiv((long long)Nt[t]*64, 256), 256, 0, stream>>>(
            ACC2 + (size_t)accRow[t]*64, b2, FLAG, relA[t], relB[t], d_out, oOff[t], Nt[t]);
    }
}

// Round 4
// 1366.827 us; speedup vs baseline: 6.4645x; 2.0039x over previous
//
#include <hip/hip_runtime.h>
#include <hip/hip_bf16.h>
#include <math.h>

#define NCIRC 40000
#define NMI   15000
#define NDIS  8000
#define NTOT  (NCIRC + NMI + NDIS)

typedef __hip_bfloat16 bf16;
typedef __attribute__((ext_vector_type(8))) short short8;
typedef __attribute__((ext_vector_type(4))) float f32x4;
typedef __attribute__((ext_vector_type(8))) unsigned short us8v;

static __device__ __forceinline__ float b2f(bf16 x){ return __bfloat162float(x); }
static __device__ __forceinline__ float us2f(unsigned short u){ return __uint_as_float(((unsigned)u) << 16); }
static __device__ __forceinline__ unsigned short f2bu(float v){
    bf16 t = __float2bfloat16(v);
    return *reinterpret_cast<unsigned short*>(&t);
}
static __device__ __forceinline__ float ldx(const void* p, size_t i, int f32){
    return f32 ? ((const float*)p)[i] : __bfloat162float(((const bf16*)p)[i]);
}
static inline unsigned cdiv(long long a, long long b){ return (unsigned)((a + b - 1) / b); }

// ---------- dtype detection ----------
__global__ void detect_dtype(const unsigned short* __restrict__ u, int* __restrict__ flag){
    int bad = 0;
    for (int i = threadIdx.x; i < 4096; i += 256){
        int e = (u[i] >> 7) & 0xFF;
        if (e >= 0x90) bad = 1;
    }
    if (bad) atomicOr(flag, 1);
}

// ---------- CSR build ----------
__global__ void csr_count(const int* __restrict__ dst, int E, int* __restrict__ cnt){
    int e = blockIdx.x * blockDim.x + threadIdx.x;
    if (e < E) atomicAdd(&cnt[dst[e]], 1);
}

// exclusive prefix via wave scans; block 1024
__global__ void csr_scan(const int* __restrict__ cnt, int* __restrict__ off, int N){
    __shared__ int wsum[16];
    __shared__ int base;
    int tid = threadIdx.x, lane = tid & 63, wv = tid >> 6;
    if (tid == 0) base = 0;
    __syncthreads();
    for (int c0 = 0; c0 < N; c0 += 1024){
        int i = c0 + tid;
        int v = (i < N) ? cnt[i] : 0;
        int x = v;
        #pragma unroll
        for (int d = 1; d < 64; d <<= 1){
            int y = __shfl_up(x, d, 64);
            if (lane >= d) x += y;
        }
        if (lane == 63) wsum[wv] = x;
        __syncthreads();
        if (tid == 0){
            int s = 0;
            #pragma unroll
            for (int k = 0; k < 16; k++){ s += wsum[k]; wsum[k] = s; }
        }
        __syncthreads();
        int woff = (wv == 0) ? 0 : wsum[wv - 1];
        if (i < N) off[i + 1] = base + woff + x;
        int total = wsum[15];
        __syncthreads();
        if (tid == 0) base += total;
        __syncthreads();
    }
    if (threadIdx.x == 0) off[0] = 0;
}

// store resolved src ids grouped by dst (kills one indirection in gathers)
__global__ void csr_fill(const int* __restrict__ src, const int* __restrict__ dst, int E,
                         const int* __restrict__ off, int* __restrict__ pos, int* __restrict__ srcs){
    int e = blockIdx.x * blockDim.x + threadIdx.x;
    if (e >= E) return;
    int d = dst[e];
    int p = atomicAdd(&pos[d], 1);
    srcs[off[d] + p] = src[e];
}

// ---------- weight transpose: WT[r][n][k] (bf16) = W[r][k][n] ----------
__global__ void transpose_w(const void* __restrict__ W, const int* __restrict__ flag,
                            bf16* __restrict__ WT, int Kd, int Nd, int nrel){
    int f32 = *flag;
    long long idx = (long long)blockIdx.x * 256 + threadIdx.x;
    long long tot = (long long)nrel * Kd * Nd;
    if (idx >= tot) return;
    int per = Kd * Nd;
    int r = (int)(idx / per);
    int rem = (int)(idx % per);
    int n = rem / Kd, k = rem % Kd;
    float v = ldx(W, (size_t)r*per + (size_t)k*Nd + n, f32);
    WT[idx] = __float2bfloat16(v);
}

// ---------- weight folding ----------
__global__ void compute_wa1(const void* __restrict__ W1, const void* __restrict__ as1,
                            const void* __restrict__ ad1, int r, const int* __restrict__ flag,
                            float* __restrict__ wa_s, float* __restrict__ wa_d){
    int f32 = *flag;
    int t = threadIdx.x;            // 0..511 -> f*4+h
    int f = t >> 2, h = t & 3;
    size_t wb = (size_t)r*128*256 + (size_t)f*256 + h*64;
    size_t ab = (size_t)r*256 + h*64;
    float ss = 0.f, sd = 0.f;
    for (int c = 0; c < 64; c++){
        float w = ldx(W1, wb + c, f32);
        ss += w * ldx(as1, ab + c, f32);
        sd += w * ldx(ad1, ab + c, f32);
    }
    wa_s[t] = ss; wa_d[t] = sd;
}

__global__ void compute_wa2(const void* __restrict__ W2, const void* __restrict__ as2,
                            const void* __restrict__ ad2, int r, const int* __restrict__ flag,
                            float* __restrict__ wa_s, float* __restrict__ wa_d){
    int f32 = *flag;
    int f = threadIdx.x;            // 0..255
    size_t wb = (size_t)r*256*64 + (size_t)f*64;
    float ss = 0.f, sd = 0.f;
    for (int c = 0; c < 64; c++){
        float w = ldx(W2, wb + c, f32);
        ss += w * ldx(as2, (size_t)r*64 + c, f32);
        sd += w * ldx(ad2, (size_t)r*64 + c, f32);
    }
    wa_s[f] = ss; wa_d[f] = sd;
}

// ---------- attention logits (1 thread per node, all heads) ----------
__global__ void compute_al1v(const void* __restrict__ X, const int* __restrict__ flag,
                             const float* __restrict__ wa, float* __restrict__ al, int N){
    __shared__ float swa[512];
    int f32 = *flag;
    for (int i = threadIdx.x; i < 512; i += 256) swa[i] = wa[i];
    __syncthreads();
    int n = blockIdx.x * 256 + threadIdx.x;
    if (n >= N) return;
    float s0 = 0.f, s1 = 0.f, s2 = 0.f, s3 = 0.f;
    if (f32){
        const float* xr = (const float*)X + (size_t)n*128;
        for (int f = 0; f < 128; f++){
            float v = xr[f];
            s0 += v*swa[f*4+0]; s1 += v*swa[f*4+1]; s2 += v*swa[f*4+2]; s3 += v*swa[f*4+3];
        }
    } else {
        const unsigned short* xr = (const unsigned short*)X + (size_t)n*128;
        for (int f0 = 0; f0 < 128; f0 += 8){
            us8v v = *(const us8v*)(xr + f0);
            #pragma unroll
            for (int j = 0; j < 8; j++){
                float vv = us2f(v[j]); int f = f0 + j;
                s0 += vv*swa[f*4+0]; s1 += vv*swa[f*4+1]; s2 += vv*swa[f*4+2]; s3 += vv*swa[f*4+3];
            }
        }
    }
    *(float4*)(al + (size_t)n*4) = make_float4(s0, s1, s2, s3);
}

__global__ void compute_al2v(const float* __restrict__ X, const float* __restrict__ wa,
                             float* __restrict__ al, int N){
    __shared__ float swa[256];
    if (threadIdx.x < 256) swa[threadIdx.x] = wa[threadIdx.x];
    __syncthreads();
    int n = blockIdx.x * 256 + threadIdx.x;
    if (n >= N) return;
    const float4* xr = (const float4*)(X + (size_t)n*256);
    float s = 0.f;
    for (int f0 = 0; f0 < 64; f0++){
        float4 v = xr[f0];
        s += v.x*swa[f0*4+0] + v.y*swa[f0*4+1] + v.z*swa[f0*4+2] + v.w*swa[f0*4+3];
    }
    al[n] = s;
}

// ---------- MFMA GEMM: C[M,N](bf16) = A[M,K] @ WT^T, WT[n][k] bf16 ----------
// block 256 = 4 waves; tile 64x64; wave w -> rows [w*16,w*16+16), 4 col-tiles of 16.
// amode: 0 = bf16 A, 1 = f32 A, 2 = per-flag
__global__ void gemm_mfma(const void* __restrict__ A, int amode,
                          const bf16* __restrict__ WT, size_t bOff,
                          const int* __restrict__ flag, bf16* __restrict__ C,
                          int M, int N, int K){
    int af32 = (amode == 2) ? *flag : amode;
    __shared__ unsigned short As[64][40];
    __shared__ unsigned short Bs[64][40];
    int tid = threadIdx.x;
    int w = tid >> 6, lane = tid & 63;
    int quad = lane >> 4, l16 = lane & 15;
    int m0 = blockIdx.y * 64, n0 = blockIdx.x * 64;
    int srow = tid >> 2, skc = (tid & 3) * 8;       // staging coords
    const unsigned short* WTu = (const unsigned short*)WT + bOff;
    f32x4 acc[4] = {};
    for (int k0 = 0; k0 < K; k0 += 32){
        // stage A (convert to bf16 if needed)
        {
            int gr = m0 + srow;
            us8v av;
            if (gr < M){
                if (af32){
                    const float* ap = (const float*)A + (size_t)gr*K + k0 + skc;
                    #pragma unroll
                    for (int j = 0; j < 8; j++) av[j] = f2bu(ap[j]);
                } else {
                    av = *(const us8v*)((const unsigned short*)A + (size_t)gr*K + k0 + skc);
                }
            } else {
                #pragma unroll
                for (int j = 0; j < 8; j++) av[j] = 0;
            }
            *(us8v*)&As[srow][skc] = av;
        }
        // stage B from transposed weights: contiguous in k
        *(us8v*)&Bs[srow][skc] = *(const us8v*)(WTu + (size_t)(n0 + srow)*K + k0 + skc);
        __syncthreads();
        short8 af = *(const short8*)&As[w*16 + l16][quad*8];
        #pragma unroll
        for (int c = 0; c < 4; c++){
            short8 bf = *(const short8*)&Bs[c*16 + l16][quad*8];
            acc[c] = __builtin_amdgcn_mfma_f32_16x16x32_bf16(af, bf, acc[c], 0, 0, 0);
        }
        __syncthreads();
    }
    // epilogue: D col=lane&15, row=quad*4+reg
    #pragma unroll
    for (int c = 0; c < 4; c++){
        #pragma unroll
        for (int i = 0; i < 4; i++){
            int m = m0 + w*16 + quad*4 + i;
            if (m < M) C[(size_t)m*N + n0 + c*16 + l16] = __float2bfloat16(acc[c][i]);
        }
    }
}

// ---------- GAT aggregation (1 wave per dst) ----------
// pass1: lane-parallel den + butterfly reduce. pass2: unrolled x4 row gathers.
__global__ void gat_gather256(const int* __restrict__ srcs, const int* __restrict__ off,
                              const float* __restrict__ als, const float* __restrict__ ald,
                              const bf16* __restrict__ HS, float* __restrict__ acc,
                              int add, int Nd){
    int t = blockIdx.x * blockDim.x + threadIdx.x;
    int w = t >> 6;
    if (w >= Nd) return;
    int lane = t & 63;
    int h = lane >> 4;
    float4 ald4 = *(const float4*)(ald + (size_t)w*4);
    int beg = off[w], end = off[w+1];
    // pass 1
    float d0 = 0.f, d1 = 0.f, d2 = 0.f, d3 = 0.f;
    for (int i = beg + lane; i < end; i += 64){
        int s = srcs[i];
        float4 a4 = *(const float4*)(als + (size_t)s*4);
        float a;
        a = a4.x + ald4.x; d0 += __expf(a > 0.f ? a : 0.2f*a);
        a = a4.y + ald4.y; d1 += __expf(a > 0.f ? a : 0.2f*a);
        a = a4.z + ald4.z; d2 += __expf(a > 0.f ? a : 0.2f*a);
        a = a4.w + ald4.w; d3 += __expf(a > 0.f ? a : 0.2f*a);
    }
    #pragma unroll
    for (int mk = 32; mk > 0; mk >>= 1){
        d0 += __shfl_xor(d0, mk, 64); d1 += __shfl_xor(d1, mk, 64);
        d2 += __shfl_xor(d2, mk, 64); d3 += __shfl_xor(d3, mk, 64);
    }
    float inv  = 1.0f / (((h < 2) ? (h == 0 ? d0 : d1) : (h == 2 ? d2 : d3)) + 1e-16f);
    float aldv = (h < 2) ? (h == 0 ? ald4.x : ald4.y) : (h == 2 ? ald4.z : ald4.w);
    // pass 2
    float a0 = 0.f, a1 = 0.f, a2 = 0.f, a3 = 0.f;
    const unsigned short* Hu = (const unsigned short*)HS;
    int i = beg;
    for (; i + 4 <= end; i += 4){
        int s0 = srcs[i], s1 = srcs[i+1], s2 = srcs[i+2], s3 = srcs[i+3];
        ushort4 h0 = *(const ushort4*)(Hu + (size_t)s0*256 + lane*4);
        ushort4 h1 = *(const ushort4*)(Hu + (size_t)s1*256 + lane*4);
        ushort4 h2 = *(const ushort4*)(Hu + (size_t)s2*256 + lane*4);
        ushort4 h3 = *(const ushort4*)(Hu + (size_t)s3*256 + lane*4);
        float x0 = als[(size_t)s0*4 + h] + aldv;
        float x1 = als[(size_t)s1*4 + h] + aldv;
        float x2 = als[(size_t)s2*4 + h] + aldv;
        float x3 = als[(size_t)s3*4 + h] + aldv;
        float e0 = __expf(x0 > 0.f ? x0 : 0.2f*x0) * inv;
        float e1 = __expf(x1 > 0.f ? x1 : 0.2f*x1) * inv;
        float e2 = __expf(x2 > 0.f ? x2 : 0.2f*x2) * inv;
        float e3 = __expf(x3 > 0.f ? x3 : 0.2f*x3) * inv;
        a0 += e0*us2f(h0.x) + e1*us2f(h1.x) + e2*us2f(h2.x) + e3*us2f(h3.x);
        a1 += e0*us2f(h0.y) + e1*us2f(h1.y) + e2*us2f(h2.y) + e3*us2f(h3.y);
        a2 += e0*us2f(h0.z) + e1*us2f(h1.z) + e2*us2f(h2.z) + e3*us2f(h3.z);
        a3 += e0*us2f(h0.w) + e1*us2f(h1.w) + e2*us2f(h2.w) + e3*us2f(h3.w);
    }
    for (; i < end; i++){
        int s = srcs[i];
        ushort4 hv = *(const ushort4*)(Hu + (size_t)s*256 + lane*4);
        float x = als[(size_t)s*4 + h] + aldv;
        float e = __expf(x > 0.f ? x : 0.2f*x) * inv;
        a0 += e*us2f(hv.x); a1 += e*us2f(hv.y); a2 += e*us2f(hv.z); a3 += e*us2f(hv.w);
    }
    float* ap = acc + (size_t)w*256 + lane*4;
    if (add){ ap[0] += a0; ap[1] += a1; ap[2] += a2; ap[3] += a3; }
    else    { ap[0]  = a0; ap[1]  = a1; ap[2]  = a2; ap[3]  = a3; }
}

__global__ void gat_gather64(const int* __restrict__ srcs, const int* __restrict__ off,
                             const float* __restrict__ als, const float* __restrict__ ald,
                             const bf16* __restrict__ HS, float* __restrict__ acc,
                             int add, int Nd){
    int t = blockIdx.x * blockDim.x + threadIdx.x;
    int w = t >> 6;
    if (w >= Nd) return;
    int lane = t & 63;
    float aldv = ald[w];
    int beg = off[w], end = off[w+1];
    float den = 0.f;
    for (int i = beg + lane; i < end; i += 64){
        float a = als[srcs[i]] + aldv;
        den += __expf(a > 0.f ? a : 0.2f*a);
    }
    #pragma unroll
    for (int mk = 32; mk > 0; mk >>= 1) den += __shfl_xor(den, mk, 64);
    float inv = 1.0f / (den + 1e-16f);
    float a0 = 0.f;
    const unsigned short* Hu = (const unsigned short*)HS;
    int i = beg;
    for (; i + 4 <= end; i += 4){
        int s0 = srcs[i], s1 = srcs[i+1], s2 = srcs[i+2], s3 = srcs[i+3];
        unsigned short h0 = Hu[(size_t)s0*64 + lane];
        unsigned short h1 = Hu[(size_t)s1*64 + lane];
        unsigned short h2 = Hu[(size_t)s2*64 + lane];
        unsigned short h3 = Hu[(size_t)s3*64 + lane];
        float x0 = als[s0] + aldv, x1 = als[s1] + aldv;
        float x2 = als[s2] + aldv, x3 = als[s3] + aldv;
        float e0 = __expf(x0 > 0.f ? x0 : 0.2f*x0) * inv;
        float e1 = __expf(x1 > 0.f ? x1 : 0.2f*x1) * inv;
        float e2 = __expf(x2 > 0.f ? x2 : 0.2f*x2) * inv;
        float e3 = __expf(x3 > 0.f ? x3 : 0.2f*x3) * inv;
        a0 += e0*us2f(h0) + e1*us2f(h1) + e2*us2f(h2) + e3*us2f(h3);
    }
    for (; i < end; i++){
        int s = srcs[i];
        float x = als[s] + aldv;
        float e = __expf(x > 0.f ? x : 0.2f*x) * inv;
        a0 += e * us2f(Hu[(size_t)s*64 + lane]);
    }
    float* ap = acc + (size_t)w*64 + lane;
    if (add) *ap += a0; else *ap = a0;
}

// ---------- epilogues ----------
__global__ void elu_bias(float* __restrict__ acc, const void* __restrict__ b1,
                         const int* __restrict__ flag, int ra, int rb, int N){
    int f32 = *flag;
    int i = blockIdx.x * blockDim.x + threadIdx.x;
    if (i >= N*256) return;
    int c = i & 255;
    float v = acc[i] * 0.5f + 0.5f * (ldx(b1, ra*256 + c, f32) + ldx(b1, rb*256 + c, f32));
    acc[i] = v > 0.f ? v : (__expf(v) - 1.0f);
}

__global__ void finalize(const float* __restrict__ acc, const void* __restrict__ b2,
                         const int* __restrict__ flag, int ra, int rb,
                         void* __restrict__ out, size_t outOff, int N){
    int f32 = *flag;
    int t = blockIdx.x * blockDim.x + threadIdx.x;
    int n = t >> 6;
    if (n >= N) return;
    int lane = t & 63;
    float v = acc[(size_t)n*64 + lane] * 0.5f
            + 0.5f * (ldx(b2, ra*64 + lane, f32) + ldx(b2, rb*64 + lane, f32));
    float ss = v * v;
    #pragma unroll
    for (int mk = 32; mk > 0; mk >>= 1) ss += __shfl_xor(ss, mk, 64);
    float nrm = sqrtf(ss);
    nrm = nrm > 1e-12f ? nrm : 1e-12f;
    float r = v / nrm;
    size_t idx = outOff + (size_t)n*64 + lane;
    if (f32) ((float*)out)[idx] = r;
    else     ((bf16*)out)[idx] = __float2bfloat16(r);
}

// ---------- host ----------
extern "C" void kernel_launch(void* const* d_in, const int* in_sizes, int n_in,
                              void* d_out, int out_size, void* d_ws, size_t ws_size,
                              hipStream_t stream){
    const void* x[3] = {d_in[0], d_in[1], d_in[2]};
    const int Nt[3] = {NCIRC, NMI, NDIS};
    const int* ep[6]; int Ecnt[6];
    for (int r = 0; r < 6; r++){ ep[r] = (const int*)d_in[3 + r]; Ecnt[r] = in_sizes[3 + r] / 2; }
    const void* W1  = d_in[9];
    const void* as1 = d_in[10];
    const void* ad1 = d_in[11];
    const void* b1  = d_in[12];
    const void* W2  = d_in[13];
    const void* as2 = d_in[14];
    const void* ad2 = d_in[15];
    const void* b2  = d_in[16];

    const int rs[6] = {0, 1, 0, 1, 2, 2};
    const int rd[6] = {1, 2, 2, 0, 1, 0};
    const int relA[3] = {3, 0, 1};
    const int relB[3] = {5, 4, 2};
    const int addF[6] = {0, 0, 1, 0, 1, 1};
    const int accRow[3] = {0, NCIRC, NCIRC + NMI};

    // ---- workspace layout (~98 MB) ----
    float* ws   = (float*)d_ws;
    int*   FLAG = (int*)ws;                          // [16]
    float* R1   = ws + 16;                           // [5,500,000]
    float* ALS  = R1 + 5500000;                      // [160,000]
    float* ALD  = ALS + 160000;                      // [160,000]
    float* ACC1 = ALD + 160000;                      // [16,128,000] (becomes X2)
    float* WAs  = ACC1 + (size_t)NTOT*256;           // [512]
    float* WAd  = WAs + 512;                         // [512]
    bf16*  W1T  = (bf16*)(WAd + 512);                // [6*256*128] bf16
    bf16*  W2T  = W1T + 6*256*128;                   // [6*64*256] bf16
    int*   CNT  = (int*)(W2T + 6*64*256);            // [40,064]
    int*   OFF  = CNT + 40064;                       // [6*40,064]
    int*   SRCS = OFF + 6*40064;                     // [2,000,000]
    bf16*  HS1  = (bf16*)R1;
    float* ACC2 = R1;
    bf16*  HS2  = (bf16*)(R1 + 4032000);

    hipMemsetAsync(FLAG, 0, sizeof(int), stream);
    detect_dtype<<<1, 256, 0, stream>>>((const unsigned short*)d_in[0], FLAG);

    // ---- pre-transpose weights to bf16 [n][k] ----
    transpose_w<<<cdiv(6LL*128*256, 256), 256, 0, stream>>>(W1, FLAG, W1T, 128, 256, 6);
    transpose_w<<<cdiv(6LL*256*64, 256), 256, 0, stream>>>(W2, FLAG, W2T, 256, 64, 6);

    // ---- CSR (edges grouped by dst, src ids resolved) ----
    size_t eOff[6]; size_t acc_e = 0;
    for (int r = 0; r < 6; r++){ eOff[r] = acc_e; acc_e += Ecnt[r]; }
    for (int r = 0; r < 6; r++){
        int Nd = Nt[rd[r]], E = Ecnt[r];
        const int* srcp = ep[r];
        const int* dstp = ep[r] + E;
        int* offR = OFF + r*40064;
        hipMemsetAsync(CNT, 0, (size_t)Nd*sizeof(int), stream);
        csr_count<<<cdiv(E, 256), 256, 0, stream>>>(dstp, E, CNT);
        csr_scan<<<1, 1024, 0, stream>>>(CNT, offR, Nd);
        hipMemsetAsync(CNT, 0, (size_t)Nd*sizeof(int), stream);
        csr_fill<<<cdiv(E, 256), 256, 0, stream>>>(srcp, dstp, E, offR, CNT, SRCS + eOff[r]);
    }

    // ===== layer 1 =====
    for (int r = 0; r < 6; r++){
        int s = rs[r], d = rd[r];
        int Ns = Nt[s], Nd = Nt[d];

        compute_wa1<<<1, 512, 0, stream>>>(W1, as1, ad1, r, FLAG, WAs, WAd);
        compute_al1v<<<cdiv(Ns, 256), 256, 0, stream>>>(x[s], FLAG, WAs, ALS, Ns);
        compute_al1v<<<cdiv(Nd, 256), 256, 0, stream>>>(x[d], FLAG, WAd, ALD, Nd);
        gemm_mfma<<<dim3(4, cdiv(Ns, 64)), 256, 0, stream>>>(
            x[s], 2, W1T, (size_t)r*256*128, FLAG, HS1, Ns, 256, 128);
        gat_gather256<<<cdiv((long long)Nd*64, 256), 256, 0, stream>>>(
            SRCS + eOff[r], OFF + r*40064, ALS, ALD, HS1,
            ACC1 + (size_t)accRow[d]*256, addF[r], Nd);
    }
    for (int t = 0; t < 3; t++){
        elu_bias<<<cdiv((long long)Nt[t]*256, 256), 256, 0, stream>>>(
            ACC1 + (size_t)accRow[t]*256, b1, FLAG, relA[t], relB[t], Nt[t]);
    }

    // ===== layer 2 =====
    for (int r = 0; r < 6; r++){
        int s = rs[r], d = rd[r];
        int Ns = Nt[s], Nd = Nt[d];
        const float* X2s = ACC1 + (size_t)accRow[s]*256;
        const float* X2d = ACC1 + (size_t)accRow[d]*256;

        compute_wa2<<<1, 256, 0, stream>>>(W2, as2, ad2, r, FLAG, WAs, WAd);
        compute_al2v<<<cdiv(Ns, 256), 256, 0, stream>>>(X2s, WAs, ALS, Ns);
        compute_al2v<<<cdiv(Nd, 256), 256, 0, stream>>>(X2d, WAd, ALD, Nd);
        gemm_mfma<<<dim3(1, cdiv(Ns, 64)), 256, 0, stream>>>(
            X2s, 1, W2T, (size_t)r*64*256, FLAG, HS2, Ns, 64, 256);
        gat_gather64<<<cdiv((long long)Nd*64, 256), 256, 0, stream>>>(
            SRCS + eOff[r], OFF + r*40064, ALS, ALD, HS2,
            ACC2 + (size_t)accRow[d]*64, addF[r], Nd);
    }

    // ===== finalize =====
    size_t oOff[3] = {0, (size_t)NCIRC*64, (size_t)(NCIRC + NMI)*64};
    for (int t = 0; t < 3; t++){
        finalize<<<cdiv((long long)Nt[t]*64, 256), 256, 0, stream>>>(
            ACC2 + (size_t)accRow[t]*64, b2, FLAG, relA[t], relB[t], d_out, oOff[t], Nt[t]);
    }
}

// Round 5
// 801.154 us; speedup vs baseline: 11.0289x; 1.7061x over previous
//
#include <hip/hip_runtime.h>
#include <hip/hip_bf16.h>
#include <math.h>

#define NCIRC 40000
#define NMI   15000
#define NDIS  8000
#define NTOT  (NCIRC + NMI + NDIS)
#define OFFSTR 40064

typedef __hip_bfloat16 bf16;
typedef __attribute__((ext_vector_type(8))) short short8;
typedef __attribute__((ext_vector_type(4))) float f32x4;
typedef __attribute__((ext_vector_type(8))) unsigned short us8v;

static __device__ __forceinline__ float us2f(unsigned short u){ return __uint_as_float(((unsigned)u) << 16); }
static __device__ __forceinline__ unsigned short f2bu(float v){
    bf16 t = __float2bfloat16(v);
    return *reinterpret_cast<unsigned short*>(&t);
}
static __device__ __forceinline__ float ldx(const void* p, size_t i, int f32){
    return f32 ? ((const float*)p)[i] : __bfloat162float(((const bf16*)p)[i]);
}
static inline unsigned cdiv(long long a, long long b){ return (unsigned)((a + b - 1) / b); }

// ---------- arg structs (passed by value) ----------
struct CsrArgs {
    const int* src[6]; const int* dst[6];
    int ecnt[6]; int eoff[6]; int nd[6];
};
struct Al1Args { const void* x[3]; const float* wa[3][4]; float* out[3][4]; int nt[3]; };
struct Al2Args { const float* x[3]; const float* wa[3][4]; float* out[3][4]; int nt[3]; };
struct GemmArgs { const void* A[6]; unsigned long long bOff[6]; unsigned long long cOff[6]; int M[6]; };
struct G3Args {
    const int* srcs[3]; const int* off[3]; const float* als[3]; const float* ald[3];
    const unsigned short* hs[3]; float* acc[3]; int nd[3];
};

// ---------- dtype detection ----------
__global__ void detect_dtype(const unsigned short* __restrict__ u, int* __restrict__ flag){
    int bad = 0;
    for (int i = threadIdx.x; i < 4096; i += 256){
        int e = (u[i] >> 7) & 0xFF;
        if (e >= 0x90) bad = 1;
    }
    if (bad) atomicOr(flag, 1);
}

// ---------- CSR build (batched over 6 relations) ----------
__global__ void csr_count_all(CsrArgs a, int* __restrict__ cnt){
    int r = blockIdx.y;
    int e = blockIdx.x * 256 + threadIdx.x;
    if (e < a.ecnt[r]) atomicAdd(&cnt[r*OFFSTR + a.dst[r][e]], 1);
}

__global__ void csr_scan_all(CsrArgs a, const int* __restrict__ cnt, int* __restrict__ off){
    int r = blockIdx.x;
    int N = a.nd[r];
    const int* c = cnt + r*OFFSTR;
    int* o = off + r*OFFSTR;
    __shared__ int wsum[16];
    __shared__ int base;
    int tid = threadIdx.x, lane = tid & 63, wv = tid >> 6;
    if (tid == 0) base = 0;
    __syncthreads();
    for (int c0 = 0; c0 < N; c0 += 1024){
        int i = c0 + tid;
        int x = (i < N) ? c[i] : 0;
        #pragma unroll
        for (int d = 1; d < 64; d <<= 1){
            int y = __shfl_up(x, d, 64);
            if (lane >= d) x += y;
        }
        if (lane == 63) wsum[wv] = x;
        __syncthreads();
        if (tid == 0){
            int s = 0;
            #pragma unroll
            for (int k = 0; k < 16; k++){ s += wsum[k]; wsum[k] = s; }
        }
        __syncthreads();
        int woff = (wv == 0) ? 0 : wsum[wv - 1];
        if (i < N) o[i + 1] = base + woff + x;
        int total = wsum[15];
        __syncthreads();
        if (tid == 0) base += total;
        __syncthreads();
    }
    if (tid == 0) o[0] = 0;
}

__global__ void csr_fill_all(CsrArgs a, const int* __restrict__ off,
                             int* __restrict__ pos, int* __restrict__ srcs){
    int r = blockIdx.y;
    int e = blockIdx.x * 256 + threadIdx.x;
    if (e >= a.ecnt[r]) return;
    int d = a.dst[r][e];
    int p = atomicAdd(&pos[r*OFFSTR + d], 1);
    srcs[a.eoff[r] + off[r*OFFSTR + d] + p] = a.src[r][e];
}

// ---------- weight transpose: WT[r][n][k] (bf16) = W[r][k][n] ----------
__global__ void transpose_w(const void* __restrict__ W, const int* __restrict__ flag,
                            bf16* __restrict__ WT, int Kd, int Nd, int nrel){
    int f32 = *flag;
    long long idx = (long long)blockIdx.x * 256 + threadIdx.x;
    long long tot = (long long)nrel * Kd * Nd;
    if (idx >= tot) return;
    int per = Kd * Nd;
    int r = (int)(idx / per);
    int rem = (int)(idx % per);
    int n = rem / Kd, k = rem % Kd;
    float v = ldx(W, (size_t)r*per + (size_t)k*Nd + n, f32);
    WT[idx] = __float2bfloat16(v);
}

// ---------- weight folding (batched: blockIdx.x = relation) ----------
__global__ void compute_wa1_all(const void* __restrict__ W1, const void* __restrict__ as1,
                                const void* __restrict__ ad1, const int* __restrict__ flag,
                                float* __restrict__ wa_s, float* __restrict__ wa_d){
    int f32 = *flag;
    int r = blockIdx.x;
    int t = threadIdx.x;            // 0..511 -> f*4+h
    int f = t >> 2, h = t & 3;
    size_t wb = (size_t)r*128*256 + (size_t)f*256 + h*64;
    size_t ab = (size_t)r*256 + h*64;
    float ss = 0.f, sd = 0.f;
    for (int c = 0; c < 64; c++){
        float w = ldx(W1, wb + c, f32);
        ss += w * ldx(as1, ab + c, f32);
        sd += w * ldx(ad1, ab + c, f32);
    }
    wa_s[r*512 + t] = ss; wa_d[r*512 + t] = sd;
}

__global__ void compute_wa2_all(const void* __restrict__ W2, const void* __restrict__ as2,
                                const void* __restrict__ ad2, const int* __restrict__ flag,
                                float* __restrict__ wa_s, float* __restrict__ wa_d){
    int f32 = *flag;
    int r = blockIdx.x;
    int f = threadIdx.x;            // 0..255
    size_t wb = (size_t)r*256*64 + (size_t)f*64;
    float ss = 0.f, sd = 0.f;
    for (int c = 0; c < 64; c++){
        float w = ldx(W2, wb + c, f32);
        ss += w * ldx(as2, (size_t)r*64 + c, f32);
        sd += w * ldx(ad2, (size_t)r*64 + c, f32);
    }
    wa_s[r*256 + f] = ss; wa_d[r*256 + f] = sd;
}

// ---------- layer-1 logits: per type, each node row read ONCE, 4 logit sets ----------
__global__ void al1_all(Al1Args a, const int* __restrict__ flag){
    int t = blockIdx.y;
    int N = a.nt[t];
    __shared__ float swa[4][512];
    for (int i = threadIdx.x; i < 2048; i += 256) swa[i >> 9][i & 511] = a.wa[t][i >> 9][i & 511];
    __syncthreads();
    int n = blockIdx.x * 256 + threadIdx.x;
    if (n >= N) return;
    int f32 = *flag;
    float s[4][4] = {};
    if (f32){
        const float* xr = (const float*)a.x[t] + (size_t)n*128;
        for (int f = 0; f < 128; f++){
            float v = xr[f];
            #pragma unroll
            for (int j = 0; j < 4; j++){
                s[j][0] += v*swa[j][f*4+0]; s[j][1] += v*swa[j][f*4+1];
                s[j][2] += v*swa[j][f*4+2]; s[j][3] += v*swa[j][f*4+3];
            }
        }
    } else {
        const unsigned short* xr = (const unsigned short*)a.x[t] + (size_t)n*128;
        for (int f0 = 0; f0 < 128; f0 += 8){
            us8v v8 = *(const us8v*)(xr + f0);
            #pragma unroll
            for (int jj = 0; jj < 8; jj++){
                float v = us2f(v8[jj]); int f = f0 + jj;
                #pragma unroll
                for (int j = 0; j < 4; j++){
                    s[j][0] += v*swa[j][f*4+0]; s[j][1] += v*swa[j][f*4+1];
                    s[j][2] += v*swa[j][f*4+2]; s[j][3] += v*swa[j][f*4+3];
                }
            }
        }
    }
    #pragma unroll
    for (int j = 0; j < 4; j++)
        *(float4*)(a.out[t][j] + (size_t)n*4) = make_float4(s[j][0], s[j][1], s[j][2], s[j][3]);
}

// ---------- layer-2 logits: per type, 4 scalar logits per node ----------
__global__ void al2_all(Al2Args a){
    int t = blockIdx.y;
    int N = a.nt[t];
    __shared__ float swa[4][256];
    for (int i = threadIdx.x; i < 1024; i += 256) swa[i >> 8][i & 255] = a.wa[t][i >> 8][i & 255];
    __syncthreads();
    int n = blockIdx.x * 256 + threadIdx.x;
    if (n >= N) return;
    const float4* xr = (const float4*)(a.x[t] + (size_t)n*256);
    float s0 = 0.f, s1 = 0.f, s2 = 0.f, s3 = 0.f;
    for (int f0 = 0; f0 < 64; f0++){
        float4 v = xr[f0];
        s0 += v.x*swa[0][f0*4+0] + v.y*swa[0][f0*4+1] + v.z*swa[0][f0*4+2] + v.w*swa[0][f0*4+3];
        s1 += v.x*swa[1][f0*4+0] + v.y*swa[1][f0*4+1] + v.z*swa[1][f0*4+2] + v.w*swa[1][f0*4+3];
        s2 += v.x*swa[2][f0*4+0] + v.y*swa[2][f0*4+1] + v.z*swa[2][f0*4+2] + v.w*swa[2][f0*4+3];
        s3 += v.x*swa[3][f0*4+0] + v.y*swa[3][f0*4+1] + v.z*swa[3][f0*4+2] + v.w*swa[3][f0*4+3];
    }
    a.out[t][0][n] = s0; a.out[t][1][n] = s1; a.out[t][2][n] = s2; a.out[t][3][n] = s3;
}

// ---------- batched MFMA GEMM: relation = blockIdx.z ----------
__global__ void gemm_mfma_b(GemmArgs ga, int amode, const bf16* __restrict__ WT,
                            const int* __restrict__ flag, bf16* __restrict__ Cb,
                            int N, int K){
    int r = blockIdx.z;
    int M = ga.M[r];
    int m0 = blockIdx.y * 64, n0 = blockIdx.x * 64;
    if (m0 >= M) return;
    int af32 = (amode == 2) ? *flag : amode;
    const void* A = ga.A[r];
    const unsigned short* WTu = (const unsigned short*)WT + ga.bOff[r];
    bf16* C = Cb + ga.cOff[r];
    __shared__ unsigned short As[64][40];
    __shared__ unsigned short Bs[64][40];
    int tid = threadIdx.x;
    int w = tid >> 6, lane = tid & 63;
    int quad = lane >> 4, l16 = lane & 15;
    int srow = tid >> 2, skc = (tid & 3) * 8;
    f32x4 acc[4] = {};
    for (int k0 = 0; k0 < K; k0 += 32){
        {
            int gr = m0 + srow;
            us8v av;
            if (gr < M){
                if (af32){
                    const float* ap = (const float*)A + (size_t)gr*K + k0 + skc;
                    #pragma unroll
                    for (int j = 0; j < 8; j++) av[j] = f2bu(ap[j]);
                } else {
                    av = *(const us8v*)((const unsigned short*)A + (size_t)gr*K + k0 + skc);
                }
            } else {
                #pragma unroll
                for (int j = 0; j < 8; j++) av[j] = 0;
            }
            *(us8v*)&As[srow][skc] = av;
        }
        *(us8v*)&Bs[srow][skc] = *(const us8v*)(WTu + (size_t)(n0 + srow)*K + k0 + skc);
        __syncthreads();
        short8 af = *(const short8*)&As[w*16 + l16][quad*8];
        #pragma unroll
        for (int c = 0; c < 4; c++){
            short8 bf = *(const short8*)&Bs[c*16 + l16][quad*8];
            acc[c] = __builtin_amdgcn_mfma_f32_16x16x32_bf16(af, bf, acc[c], 0, 0, 0);
        }
        __syncthreads();
    }
    #pragma unroll
    for (int c = 0; c < 4; c++){
        #pragma unroll
        for (int i = 0; i < 4; i++){
            int m = m0 + w*16 + quad*4 + i;
            if (m < M) C[(size_t)m*N + n0 + c*16 + l16] = __float2bfloat16(acc[c][i]);
        }
    }
}

// ---------- batched gathers: group member = blockIdx.y (3 disjoint dst types) ----------
__global__ void gat_gather256_b(G3Args g, int add){
    int gi = blockIdx.y;
    int t = blockIdx.x * 256 + threadIdx.x;
    int w = t >> 6;
    if (w >= g.nd[gi]) return;
    int lane = t & 63;
    int h = lane >> 4;
    const float* als = g.als[gi];
    const int* srcs = g.srcs[gi];
    float4 ald4 = *(const float4*)(g.ald[gi] + (size_t)w*4);
    int beg = g.off[gi][w], end = g.off[gi][w+1];
    float d0 = 0.f, d1 = 0.f, d2 = 0.f, d3 = 0.f;
    for (int i = beg + lane; i < end; i += 64){
        int s = srcs[i];
        float4 a4 = *(const float4*)(als + (size_t)s*4);
        float a;
        a = a4.x + ald4.x; d0 += __expf(a > 0.f ? a : 0.2f*a);
        a = a4.y + ald4.y; d1 += __expf(a > 0.f ? a : 0.2f*a);
        a = a4.z + ald4.z; d2 += __expf(a > 0.f ? a : 0.2f*a);
        a = a4.w + ald4.w; d3 += __expf(a > 0.f ? a : 0.2f*a);
    }
    #pragma unroll
    for (int mk = 32; mk > 0; mk >>= 1){
        d0 += __shfl_xor(d0, mk, 64); d1 += __shfl_xor(d1, mk, 64);
        d2 += __shfl_xor(d2, mk, 64); d3 += __shfl_xor(d3, mk, 64);
    }
    float inv  = 1.0f / (((h < 2) ? (h == 0 ? d0 : d1) : (h == 2 ? d2 : d3)) + 1e-16f);
    float aldv = (h < 2) ? (h == 0 ? ald4.x : ald4.y) : (h == 2 ? ald4.z : ald4.w);
    float a0 = 0.f, a1 = 0.f, a2 = 0.f, a3 = 0.f;
    const unsigned short* Hu = g.hs[gi];
    int i = beg;
    for (; i + 4 <= end; i += 4){
        int s0 = srcs[i], s1 = srcs[i+1], s2 = srcs[i+2], s3 = srcs[i+3];
        ushort4 h0 = *(const ushort4*)(Hu + (size_t)s0*256 + lane*4);
        ushort4 h1 = *(const ushort4*)(Hu + (size_t)s1*256 + lane*4);
        ushort4 h2 = *(const ushort4*)(Hu + (size_t)s2*256 + lane*4);
        ushort4 h3 = *(const ushort4*)(Hu + (size_t)s3*256 + lane*4);
        float x0 = als[(size_t)s0*4 + h] + aldv;
        float x1 = als[(size_t)s1*4 + h] + aldv;
        float x2 = als[(size_t)s2*4 + h] + aldv;
        float x3 = als[(size_t)s3*4 + h] + aldv;
        float e0 = __expf(x0 > 0.f ? x0 : 0.2f*x0) * inv;
        float e1 = __expf(x1 > 0.f ? x1 : 0.2f*x1) * inv;
        float e2 = __expf(x2 > 0.f ? x2 : 0.2f*x2) * inv;
        float e3 = __expf(x3 > 0.f ? x3 : 0.2f*x3) * inv;
        a0 += e0*us2f(h0.x) + e1*us2f(h1.x) + e2*us2f(h2.x) + e3*us2f(h3.x);
        a1 += e0*us2f(h0.y) + e1*us2f(h1.y) + e2*us2f(h2.y) + e3*us2f(h3.y);
        a2 += e0*us2f(h0.z) + e1*us2f(h1.z) + e2*us2f(h2.z) + e3*us2f(h3.z);
        a3 += e0*us2f(h0.w) + e1*us2f(h1.w) + e2*us2f(h2.w) + e3*us2f(h3.w);
    }
    for (; i < end; i++){
        int s = srcs[i];
        ushort4 hv = *(const ushort4*)(Hu + (size_t)s*256 + lane*4);
        float x = als[(size_t)s*4 + h] + aldv;
        float e = __expf(x > 0.f ? x : 0.2f*x) * inv;
        a0 += e*us2f(hv.x); a1 += e*us2f(hv.y); a2 += e*us2f(hv.z); a3 += e*us2f(hv.w);
    }
    float* ap = g.acc[gi] + (size_t)w*256 + lane*4;
    if (add){ ap[0] += a0; ap[1] += a1; ap[2] += a2; ap[3] += a3; }
    else    { ap[0]  = a0; ap[1]  = a1; ap[2]  = a2; ap[3]  = a3; }
}

__global__ void gat_gather64_b(G3Args g, int add){
    int gi = blockIdx.y;
    int t = blockIdx.x * 256 + threadIdx.x;
    int w = t >> 6;
    if (w >= g.nd[gi]) return;
    int lane = t & 63;
    const float* als = g.als[gi];
    const int* srcs = g.srcs[gi];
    float aldv = g.ald[gi][w];
    int beg = g.off[gi][w], end = g.off[gi][w+1];
    float den = 0.f;
    for (int i = beg + lane; i < end; i += 64){
        float a = als[srcs[i]] + aldv;
        den += __expf(a > 0.f ? a : 0.2f*a);
    }
    #pragma unroll
    for (int mk = 32; mk > 0; mk >>= 1) den += __shfl_xor(den, mk, 64);
    float inv = 1.0f / (den + 1e-16f);
    float a0 = 0.f;
    const unsigned short* Hu = g.hs[gi];
    int i = beg;
    for (; i + 4 <= end; i += 4){
        int s0 = srcs[i], s1 = srcs[i+1], s2 = srcs[i+2], s3 = srcs[i+3];
        unsigned short h0 = Hu[(size_t)s0*64 + lane];
        unsigned short h1 = Hu[(size_t)s1*64 + lane];
        unsigned short h2 = Hu[(size_t)s2*64 + lane];
        unsigned short h3 = Hu[(size_t)s3*64 + lane];
        float x0 = als[s0] + aldv, x1 = als[s1] + aldv;
        float x2 = als[s2] + aldv, x3 = als[s3] + aldv;
        float e0 = __expf(x0 > 0.f ? x0 : 0.2f*x0) * inv;
        float e1 = __expf(x1 > 0.f ? x1 : 0.2f*x1) * inv;
        float e2 = __expf(x2 > 0.f ? x2 : 0.2f*x2) * inv;
        float e3 = __expf(x3 > 0.f ? x3 : 0.2f*x3) * inv;
        a0 += e0*us2f(h0) + e1*us2f(h1) + e2*us2f(h2) + e3*us2f(h3);
    }
    for (; i < end; i++){
        int s = srcs[i];
        float x = als[s] + aldv;
        float e = __expf(x > 0.f ? x : 0.2f*x) * inv;
        a0 += e * us2f(Hu[(size_t)s*64 + lane]);
    }
    float* ap = g.acc[gi] + (size_t)w*64 + lane;
    if (add) *ap += a0; else *ap = a0;
}

// ---------- epilogues (fused across all types) ----------
__global__ void elu_bias_all(float* __restrict__ acc, const void* __restrict__ b1,
                             const int* __restrict__ flag){
    const int relA[3] = {3, 0, 1};
    const int relB[3] = {5, 4, 2};
    int f32 = *flag;
    long long i = (long long)blockIdx.x * 256 + threadIdx.x;
    if (i >= (long long)NTOT*256) return;
    int node = (int)(i >> 8);
    int c = (int)(i & 255);
    int t = (node < NCIRC) ? 0 : (node < NCIRC + NMI ? 1 : 2);
    float v = acc[i] * 0.5f + 0.5f * (ldx(b1, relA[t]*256 + c, f32) + ldx(b1, relB[t]*256 + c, f32));
    acc[i] = v > 0.f ? v : (__expf(v) - 1.0f);
}

__global__ void finalize_all(const float* __restrict__ acc, const void* __restrict__ b2,
                             const int* __restrict__ flag, void* __restrict__ out){
    const int relA[3] = {3, 0, 1};
    const int relB[3] = {5, 4, 2};
    int f32 = *flag;
    int t0 = blockIdx.x * 256 + threadIdx.x;
    int n = t0 >> 6;
    if (n >= NTOT) return;
    int lane = t0 & 63;
    int t = (n < NCIRC) ? 0 : (n < NCIRC + NMI ? 1 : 2);
    float v = acc[(size_t)n*64 + lane] * 0.5f
            + 0.5f * (ldx(b2, relA[t]*64 + lane, f32) + ldx(b2, relB[t]*64 + lane, f32));
    float ss = v * v;
    #pragma unroll
    for (int mk = 32; mk > 0; mk >>= 1) ss += __shfl_xor(ss, mk, 64);
    float nrm = sqrtf(ss);
    nrm = nrm > 1e-12f ? nrm : 1e-12f;
    float r = v / nrm;
    size_t idx = (size_t)n*64 + lane;
    if (f32) ((float*)out)[idx] = r;
    else     ((bf16*)out)[idx] = __float2bfloat16(r);
}

// ---------- host ----------
extern "C" void kernel_launch(void* const* d_in, const int* in_sizes, int n_in,
                              void* d_out, int out_size, void* d_ws, size_t ws_size,
                              hipStream_t stream){
    const void* x[3] = {d_in[0], d_in[1], d_in[2]};
    const int Nt[3] = {NCIRC, NMI, NDIS};
    const int* ep[6]; int Ecnt[6];
    for (int r = 0; r < 6; r++){ ep[r] = (const int*)d_in[3 + r]; Ecnt[r] = in_sizes[3 + r] / 2; }
    const void* W1  = d_in[9];
    const void* as1 = d_in[10];
    const void* ad1 = d_in[11];
    const void* b1  = d_in[12];
    const void* W2  = d_in[13];
    const void* as2 = d_in[14];
    const void* ad2 = d_in[15];
    const void* b2  = d_in[16];

    const int rs[6] = {0, 1, 0, 1, 2, 2};
    const int rd[6] = {1, 2, 2, 0, 1, 0};
    const int srel[3][2] = {{0, 2}, {1, 3}, {4, 5}};   // relations where type is src
    const int drel[3][2] = {{3, 5}, {0, 4}, {1, 2}};   // relations where type is dst
    const int accRow[3] = {0, NCIRC, NCIRC + NMI};
    const int grp[2][3] = {{0, 1, 3}, {2, 4, 5}};      // disjoint dst types per group

    // ---- workspace layout (~144 MB of 256 MiB) ----
    float* ws    = (float*)d_ws;
    int*   FLAG  = (int*)ws;                            // 16
    float* WA1S  = ws + 16;                             // 6*512
    float* WA1D  = WA1S + 6*512;                        // 6*512
    float* WA2S  = WA1D + 6*512;                        // 6*256
    float* WA2D  = WA2S + 6*256;                        // 6*256
    float* ALB   = WA2D + 6*256;                        // 1,008,000 (L1: 12 bufs x4; L2 reuses)
    float* R1    = ALB + 1008000;                       // 16,128,000: HS1all bf16 | ACC2+HS2all
    float* ACC1  = R1 + 16128000;                       // 16,128,000 (becomes X2)
    bf16*  W1T   = (bf16*)(ACC1 + 16128000);            // 6*256*128 bf16
    bf16*  W2T   = W1T + 6*256*128;                     // 6*64*256 bf16
    int*   CNT   = (int*)(W2T + 6*64*256);              // 6*OFFSTR
    int*   OFF   = CNT + 6*OFFSTR;                      // 6*OFFSTR
    int*   SRCS  = OFF + 6*OFFSTR;                      // 2,000,000
    unsigned short* HS1u = (unsigned short*)R1;
    float* ACC2  = R1;
    unsigned short* HS2u = (unsigned short*)(R1 + 4032000);

    // per-relation sub-buffers
    int eOff[6]; int acc_e = 0;
    for (int r = 0; r < 6; r++){ eOff[r] = acc_e; acc_e += Ecnt[r]; }
    unsigned long long hs1off[6], hs2off[6];
    { unsigned long long o1 = 0, o2 = 0;
      for (int r = 0; r < 6; r++){ hs1off[r] = o1; o1 += (unsigned long long)Nt[rs[r]]*256;
                                   hs2off[r] = o2; o2 += (unsigned long long)Nt[rs[r]]*64; } }
    float *AL1S[6], *AL1D[6], *AL2S[6], *AL2D[6];
    { size_t o = 0;
      for (int r = 0; r < 6; r++){ AL1S[r] = ALB + o; o += (size_t)Nt[rs[r]]*4; }
      for (int r = 0; r < 6; r++){ AL1D[r] = ALB + o; o += (size_t)Nt[rd[r]]*4; }
      size_t o2 = 0;
      for (int r = 0; r < 6; r++){ AL2S[r] = ALB + o2; o2 += (size_t)Nt[rs[r]]; }
      for (int r = 0; r < 6; r++){ AL2D[r] = ALB + o2; o2 += (size_t)Nt[rd[r]]; } }

    int maxE = 0; for (int r = 0; r < 6; r++) if (Ecnt[r] > maxE) maxE = Ecnt[r];

    hipMemsetAsync(FLAG, 0, sizeof(int), stream);
    detect_dtype<<<1, 256, 0, stream>>>((const unsigned short*)d_in[0], FLAG);

    transpose_w<<<cdiv(6LL*128*256, 256), 256, 0, stream>>>(W1, FLAG, W1T, 128, 256, 6);
    transpose_w<<<cdiv(6LL*256*64, 256), 256, 0, stream>>>(W2, FLAG, W2T, 256, 64, 6);

    // ---- CSR build (batched) ----
    CsrArgs ca;
    for (int r = 0; r < 6; r++){
        ca.src[r] = ep[r]; ca.dst[r] = ep[r] + Ecnt[r];
        ca.ecnt[r] = Ecnt[r]; ca.eoff[r] = eOff[r]; ca.nd[r] = Nt[rd[r]];
    }
    hipMemsetAsync(CNT, 0, (size_t)6*OFFSTR*sizeof(int), stream);
    csr_count_all<<<dim3(cdiv(maxE, 256), 6), 256, 0, stream>>>(ca, CNT);
    csr_scan_all<<<6, 1024, 0, stream>>>(ca, CNT, OFF);
    hipMemsetAsync(CNT, 0, (size_t)6*OFFSTR*sizeof(int), stream);
    csr_fill_all<<<dim3(cdiv(maxE, 256), 6), 256, 0, stream>>>(ca, OFF, CNT, SRCS);

    // ---- weight folding ----
    compute_wa1_all<<<6, 512, 0, stream>>>(W1, as1, ad1, FLAG, WA1S, WA1D);
    compute_wa2_all<<<6, 256, 0, stream>>>(W2, as2, ad2, FLAG, WA2S, WA2D);

    // ===== layer 1 =====
    Al1Args a1;
    for (int t = 0; t < 3; t++){
        a1.x[t] = x[t]; a1.nt[t] = Nt[t];
        for (int j = 0; j < 2; j++){
            a1.wa[t][j]   = WA1S + srel[t][j]*512;  a1.out[t][j]   = AL1S[srel[t][j]];
            a1.wa[t][j+2] = WA1D + drel[t][j]*512;  a1.out[t][j+2] = AL1D[drel[t][j]];
        }
    }
    al1_all<<<dim3(cdiv(NCIRC, 256), 3), 256, 0, stream>>>(a1, FLAG);

    GemmArgs g1;
    for (int r = 0; r < 6; r++){
        g1.A[r] = x[rs[r]]; g1.bOff[r] = (unsigned long long)r*256*128;
        g1.cOff[r] = hs1off[r]; g1.M[r] = Nt[rs[r]];
    }
    gemm_mfma_b<<<dim3(4, cdiv(NCIRC, 64), 6), 256, 0, stream>>>(
        g1, 2, W1T, FLAG, (bf16*)HS1u, 256, 128);

    for (int g = 0; g < 2; g++){
        G3Args ga; int mx = 0;
        for (int k = 0; k < 3; k++){
            int r = grp[g][k];
            ga.srcs[k] = SRCS + eOff[r]; ga.off[k] = OFF + r*OFFSTR;
            ga.als[k] = AL1S[r]; ga.ald[k] = AL1D[r];
            ga.hs[k] = HS1u + hs1off[r];
            ga.acc[k] = ACC1 + (size_t)accRow[rd[r]]*256;
            ga.nd[k] = Nt[rd[r]];
            if (ga.nd[k] > mx) mx = ga.nd[k];
        }
        gat_gather256_b<<<dim3(cdiv((long long)mx*64, 256), 3), 256, 0, stream>>>(ga, g);
    }
    elu_bias_all<<<cdiv((long long)NTOT*256, 256), 256, 0, stream>>>(ACC1, b1, FLAG);

    // ===== layer 2 =====
    Al2Args a2;
    for (int t = 0; t < 3; t++){
        a2.x[t] = ACC1 + (size_t)accRow[t]*256; a2.nt[t] = Nt[t];
        for (int j = 0; j < 2; j++){
            a2.wa[t][j]   = WA2S + srel[t][j]*256;  a2.out[t][j]   = AL2S[srel[t][j]];
            a2.wa[t][j+2] = WA2D + drel[t][j]*256;  a2.out[t][j+2] = AL2D[drel[t][j]];
        }
    }
    al2_all<<<dim3(cdiv(NCIRC, 256), 3), 256, 0, stream>>>(a2);

    GemmArgs g2;
    for (int r = 0; r < 6; r++){
        g2.A[r] = ACC1 + (size_t)accRow[rs[r]]*256; g2.bOff[r] = (unsigned long long)r*64*256;
        g2.cOff[r] = hs2off[r]; g2.M[r] = Nt[rs[r]];
    }
    gemm_mfma_b<<<dim3(1, cdiv(NCIRC, 64), 6), 256, 0, stream>>>(
        g2, 1, W2T, FLAG, (bf16*)HS2u, 64, 256);

    for (int g = 0; g < 2; g++){
        G3Args ga; int mx = 0;
        for (int k = 0; k < 3; k++){
            int r = grp[g][k];
            ga.srcs[k] = SRCS + eOff[r]; ga.off[k] = OFF + r*OFFSTR;
            ga.als[k] = AL2S[r]; ga.ald[k] = AL2D[r];
            ga.hs[k] = HS2u + hs2off[r];
            ga.acc[k] = ACC2 + (size_t)accRow[rd[r]]*64;
            ga.nd[k] = Nt[rd[r]];
            if (ga.nd[k] > mx) mx = ga.nd[k];
        }
        gat_gather64_b<<<dim3(cdiv((long long)mx*64, 256), 3), 256, 0, stream>>>(ga, g);
    }

    finalize_all<<<cdiv((long long)NTOT*64, 256), 256, 0, stream>>>(ACC2, b2, FLAG, d_out);
}

// Round 6
// 755.527 us; speedup vs baseline: 11.6949x; 1.0604x over previous
//
#include <hip/hip_runtime.h>
#include <hip/hip_bf16.h>
#include <math.h>

#define NCIRC 40000
#define NMI   15000
#define NDIS  8000
#define NTOT  (NCIRC + NMI + NDIS)
#define OFFSTR 40064

typedef __hip_bfloat16 bf16;
typedef __attribute__((ext_vector_type(8))) short short8;
typedef __attribute__((ext_vector_type(4))) float f32x4;
typedef __attribute__((ext_vector_type(8))) unsigned short us8v;

static __device__ __forceinline__ float us2f(unsigned short u){ return __uint_as_float(((unsigned)u) << 16); }
static __device__ __forceinline__ unsigned short f2bu(float v){
    bf16 t = __float2bfloat16(v);
    return *reinterpret_cast<unsigned short*>(&t);
}
static __device__ __forceinline__ float ldx(const void* p, size_t i, int f32){
    return f32 ? ((const float*)p)[i] : __bfloat162float(((const bf16*)p)[i]);
}
static inline unsigned cdiv(long long a, long long b){ return (unsigned)((a + b - 1) / b); }

// ---------- arg structs ----------
struct CsrArgs {
    const int* src[6]; const int* dst[6];
    int ecnt[6]; int eoff[6]; int nd[6];
};
struct Al1Args { const void* x[3]; const float* wa[3][4]; float* out[3][4]; int nt[3]; };
struct Al2Args { const unsigned short* x[3]; const float* wa[3][4]; float* out[3][4]; int nt[3]; };
struct GemmArgs { const void* A[6]; unsigned long long bOff[6]; unsigned long long cOff[6];
                  int M[6]; int nblk[6]; };
struct G3Args {
    const unsigned short* srcs[3]; const int* off[3];
    const float* als[3]; const float* ald[3];
    const unsigned short* hs[3]; float* acc[3];
    const float* bias[3]; unsigned short* x2b[3];
    unsigned long long outOff[3];
    int nd[3];
};

// ---------- dtype detection ----------
__global__ void detect_dtype(const unsigned short* __restrict__ u, int* __restrict__ flag){
    int bad = 0;
    for (int i = threadIdx.x; i < 4096; i += 256){
        int e = (u[i] >> 7) & 0xFF;
        if (e >= 0x90) bad = 1;
    }
    if (bad) atomicOr(flag, 1);
}

// ---------- CSR build ----------
__global__ void csr_count_all(CsrArgs a, int* __restrict__ cnt){
    int r = blockIdx.y;
    int e = blockIdx.x * 256 + threadIdx.x;
    if (e < a.ecnt[r]) atomicAdd(&cnt[r*OFFSTR + a.dst[r][e]], 1);
}

__global__ void csr_scan_all(CsrArgs a, const int* __restrict__ cnt, int* __restrict__ off){
    int r = blockIdx.x;
    int N = a.nd[r];
    const int* c = cnt + r*OFFSTR;
    int* o = off + r*OFFSTR;
    __shared__ int wsum[16];
    __shared__ int base;
    int tid = threadIdx.x, lane = tid & 63, wv = tid >> 6;
    if (tid == 0) base = 0;
    __syncthreads();
    for (int c0 = 0; c0 < N; c0 += 1024){
        int i = c0 + tid;
        int x = (i < N) ? c[i] : 0;
        #pragma unroll
        for (int d = 1; d < 64; d <<= 1){
            int y = __shfl_up(x, d, 64);
            if (lane >= d) x += y;
        }
        if (lane == 63) wsum[wv] = x;
        __syncthreads();
        if (tid == 0){
            int s = 0;
            #pragma unroll
            for (int k = 0; k < 16; k++){ s += wsum[k]; wsum[k] = s; }
        }
        __syncthreads();
        int woff = (wv == 0) ? 0 : wsum[wv - 1];
        if (i < N) o[i + 1] = base + woff + x;
        int total = wsum[15];
        __syncthreads();
        if (tid == 0) base += total;
        __syncthreads();
    }
    if (tid == 0) o[0] = 0;
}

__global__ void csr_fill_all(CsrArgs a, const int* __restrict__ off,
                             int* __restrict__ pos, unsigned short* __restrict__ srcs){
    int r = blockIdx.y;
    int e = blockIdx.x * 256 + threadIdx.x;
    if (e >= a.ecnt[r]) return;
    int d = a.dst[r][e];
    int p = atomicAdd(&pos[r*OFFSTR + d], 1);
    srcs[a.eoff[r] + off[r*OFFSTR + d] + p] = (unsigned short)a.src[r][e];
}

// ---------- weight transpose ----------
__global__ void transpose_w(const void* __restrict__ W, const int* __restrict__ flag,
                            bf16* __restrict__ WT, int Kd, int Nd, int nrel){
    int f32 = *flag;
    long long idx = (long long)blockIdx.x * 256 + threadIdx.x;
    long long tot = (long long)nrel * Kd * Nd;
    if (idx >= tot) return;
    int per = Kd * Nd;
    int r = (int)(idx / per);
    int rem = (int)(idx % per);
    int n = rem / Kd, k = rem % Kd;
    float v = ldx(W, (size_t)r*per + (size_t)k*Nd + n, f32);
    WT[idx] = __float2bfloat16(v);
}

// ---------- weight folding ----------
__global__ void compute_wa1_all(const void* __restrict__ W1, const void* __restrict__ as1,
                                const void* __restrict__ ad1, const int* __restrict__ flag,
                                float* __restrict__ wa_s, float* __restrict__ wa_d){
    int f32 = *flag;
    int r = blockIdx.x;
    int t = threadIdx.x;
    int f = t >> 2, h = t & 3;
    size_t wb = (size_t)r*128*256 + (size_t)f*256 + h*64;
    size_t ab = (size_t)r*256 + h*64;
    float ss = 0.f, sd = 0.f;
    for (int c = 0; c < 64; c++){
        float w = ldx(W1, wb + c, f32);
        ss += w * ldx(as1, ab + c, f32);
        sd += w * ldx(ad1, ab + c, f32);
    }
    wa_s[r*512 + t] = ss; wa_d[r*512 + t] = sd;
}

__global__ void compute_wa2_all(const void* __restrict__ W2, const void* __restrict__ as2,
                                const void* __restrict__ ad2, const int* __restrict__ flag,
                                float* __restrict__ wa_s, float* __restrict__ wa_d){
    int f32 = *flag;
    int r = blockIdx.x;
    int f = threadIdx.x;
    size_t wb = (size_t)r*256*64 + (size_t)f*64;
    float ss = 0.f, sd = 0.f;
    for (int c = 0; c < 64; c++){
        float w = ldx(W2, wb + c, f32);
        ss += w * ldx(as2, (size_t)r*64 + c, f32);
        sd += w * ldx(ad2, (size_t)r*64 + c, f32);
    }
    wa_s[r*256 + f] = ss; wa_d[r*256 + f] = sd;
}

// ---------- per-dst-type fused bias: 0.5*(b[relA]+b[relB]) ----------
__global__ void fold_bias(const void* __restrict__ b1, const void* __restrict__ b2,
                          const int* __restrict__ flag,
                          float* __restrict__ BIAS1, float* __restrict__ BIAS2){
    const int relA[3] = {3, 0, 1};
    const int relB[3] = {5, 4, 2};
    int t = blockIdx.x, c = threadIdx.x, f32 = *flag;
    BIAS1[t*256 + c] = 0.5f*(ldx(b1, relA[t]*256 + c, f32) + ldx(b1, relB[t]*256 + c, f32));
    if (c < 64)
        BIAS2[t*64 + c] = 0.5f*(ldx(b2, relA[t]*64 + c, f32) + ldx(b2, relB[t]*64 + c, f32));
}

// ---------- layer-1 logits ----------
__global__ void al1_all(Al1Args a, const int* __restrict__ flag){
    int t = blockIdx.y;
    int N = a.nt[t];
    __shared__ float swa[4][512];
    for (int i = threadIdx.x; i < 2048; i += 256) swa[i >> 9][i & 511] = a.wa[t][i >> 9][i & 511];
    __syncthreads();
    int n = blockIdx.x * 256 + threadIdx.x;
    if (n >= N) return;
    int f32 = *flag;
    float s[4][4] = {};
    if (f32){
        const float* xr = (const float*)a.x[t] + (size_t)n*128;
        for (int f = 0; f < 128; f++){
            float v = xr[f];
            #pragma unroll
            for (int j = 0; j < 4; j++){
                s[j][0] += v*swa[j][f*4+0]; s[j][1] += v*swa[j][f*4+1];
                s[j][2] += v*swa[j][f*4+2]; s[j][3] += v*swa[j][f*4+3];
            }
        }
    } else {
        const unsigned short* xr = (const unsigned short*)a.x[t] + (size_t)n*128;
        for (int f0 = 0; f0 < 128; f0 += 8){
            us8v v8 = *(const us8v*)(xr + f0);
            #pragma unroll
            for (int jj = 0; jj < 8; jj++){
                float v = us2f(v8[jj]); int f = f0 + jj;
                #pragma unroll
                for (int j = 0; j < 4; j++){
                    s[j][0] += v*swa[j][f*4+0]; s[j][1] += v*swa[j][f*4+1];
                    s[j][2] += v*swa[j][f*4+2]; s[j][3] += v*swa[j][f*4+3];
                }
            }
        }
    }
    #pragma unroll
    for (int j = 0; j < 4; j++)
        *(float4*)(a.out[t][j] + (size_t)n*4) = make_float4(s[j][0], s[j][1], s[j][2], s[j][3]);
}

// ---------- layer-2 logits (bf16 X2) ----------
__global__ void al2_all(Al2Args a){
    int t = blockIdx.y;
    int N = a.nt[t];
    __shared__ float swa[4][256];
    for (int i = threadIdx.x; i < 1024; i += 256) swa[i >> 8][i & 255] = a.wa[t][i >> 8][i & 255];
    __syncthreads();
    int n = blockIdx.x * 256 + threadIdx.x;
    if (n >= N) return;
    const unsigned short* xr = a.x[t] + (size_t)n*256;
    float s0 = 0.f, s1 = 0.f, s2 = 0.f, s3 = 0.f;
    for (int f0 = 0; f0 < 256; f0 += 8){
        us8v v8 = *(const us8v*)(xr + f0);
        #pragma unroll
        for (int jj = 0; jj < 8; jj++){
            float v = us2f(v8[jj]); int f = f0 + jj;
            s0 += v*swa[0][f]; s1 += v*swa[1][f]; s2 += v*swa[2][f]; s3 += v*swa[3][f];
        }
    }
    a.out[t][0][n] = s0; a.out[t][1][n] = s1; a.out[t][2][n] = s2; a.out[t][3][n] = s3;
}

// ---------- packed MFMA GEMM (row-tile -> relation resolved in kernel) ----------
__global__ void gemm_mfma_b(GemmArgs ga, int amode, const bf16* __restrict__ WT,
                            const int* __restrict__ flag, bf16* __restrict__ Cb,
                            int N, int K){
    int y = blockIdx.y, r = 0;
    while (r < 5 && y >= ga.nblk[r]){ y -= ga.nblk[r]; r++; }
    int M = ga.M[r];
    int m0 = y * 64, n0 = blockIdx.x * 64;
    int af32 = (amode == 2) ? *flag : amode;
    const void* A = ga.A[r];
    const unsigned short* WTu = (const unsigned short*)WT + ga.bOff[r];
    bf16* C = Cb + ga.cOff[r];
    __shared__ unsigned short As[64][40];
    __shared__ unsigned short Bs[64][40];
    int tid = threadIdx.x;
    int w = tid >> 6, lane = tid & 63;
    int quad = lane >> 4, l16 = lane & 15;
    int srow = tid >> 2, skc = (tid & 3) * 8;
    f32x4 acc[4] = {};
    for (int k0 = 0; k0 < K; k0 += 32){
        {
            int gr = m0 + srow;
            us8v av;
            if (gr < M){
                if (af32){
                    const float* ap = (const float*)A + (size_t)gr*K + k0 + skc;
                    #pragma unroll
                    for (int j = 0; j < 8; j++) av[j] = f2bu(ap[j]);
                } else {
                    av = *(const us8v*)((const unsigned short*)A + (size_t)gr*K + k0 + skc);
                }
            } else {
                #pragma unroll
                for (int j = 0; j < 8; j++) av[j] = 0;
            }
            *(us8v*)&As[srow][skc] = av;
        }
        *(us8v*)&Bs[srow][skc] = *(const us8v*)(WTu + (size_t)(n0 + srow)*K + k0 + skc);
        __syncthreads();
        short8 af = *(const short8*)&As[w*16 + l16][quad*8];
        #pragma unroll
        for (int c = 0; c < 4; c++){
            short8 bf = *(const short8*)&Bs[c*16 + l16][quad*8];
            acc[c] = __builtin_amdgcn_mfma_f32_16x16x32_bf16(af, bf, acc[c], 0, 0, 0);
        }
        __syncthreads();
    }
    #pragma unroll
    for (int c = 0; c < 4; c++){
        #pragma unroll
        for (int i = 0; i < 4; i++){
            int m = m0 + w*16 + quad*4 + i;
            if (m < M) C[(size_t)m*N + n0 + c*16 + l16] = __float2bfloat16(acc[c][i]);
        }
    }
}

// ---------- gathers (wave-packed over 3 disjoint dst-type members) ----------
// mode 0: store raw weighted sums (fp32). mode 1: read mode-0 sums, mean+bias,
// ELU, store bf16 X2 (layer 1) -- full epilogue fusion.
__global__ void gat_gather256_b(G3Args g, int mode){
    int gw = blockIdx.x * 4 + (threadIdx.x >> 6);
    int nd0 = g.nd[0], nd01 = nd0 + g.nd[1], tot = nd01 + g.nd[2];
    if (gw >= tot) return;
    int gi, w;
    if (gw < nd0){ gi = 0; w = gw; }
    else if (gw < nd01){ gi = 1; w = gw - nd0; }
    else { gi = 2; w = gw - nd01; }
    int lane = threadIdx.x & 63;
    int h = lane >> 4;
    const float* als = g.als[gi];
    const unsigned short* srcs = g.srcs[gi];
    float4 ald4 = *(const float4*)(g.ald[gi] + (size_t)w*4);
    int beg = g.off[gi][w], end = g.off[gi][w+1];
    float d0 = 0.f, d1 = 0.f, d2 = 0.f, d3 = 0.f;
    for (int i = beg + lane; i < end; i += 64){
        int s = srcs[i];
        float4 a4 = *(const float4*)(als + (size_t)s*4);
        float a;
        a = a4.x + ald4.x; d0 += __expf(a > 0.f ? a : 0.2f*a);
        a = a4.y + ald4.y; d1 += __expf(a > 0.f ? a : 0.2f*a);
        a = a4.z + ald4.z; d2 += __expf(a > 0.f ? a : 0.2f*a);
        a = a4.w + ald4.w; d3 += __expf(a > 0.f ? a : 0.2f*a);
    }
    #pragma unroll
    for (int mk = 32; mk > 0; mk >>= 1){
        d0 += __shfl_xor(d0, mk, 64); d1 += __shfl_xor(d1, mk, 64);
        d2 += __shfl_xor(d2, mk, 64); d3 += __shfl_xor(d3, mk, 64);
    }
    float inv  = 1.0f / (((h < 2) ? (h == 0 ? d0 : d1) : (h == 2 ? d2 : d3)) + 1e-16f);
    float aldv = (h < 2) ? (h == 0 ? ald4.x : ald4.y) : (h == 2 ? ald4.z : ald4.w);
    float a0 = 0.f, a1 = 0.f, a2 = 0.f, a3 = 0.f;
    const unsigned short* Hu = g.hs[gi];
    int i = beg;
    for (; i + 4 <= end; i += 4){
        int s0 = srcs[i], s1 = srcs[i+1], s2 = srcs[i+2], s3 = srcs[i+3];
        ushort4 h0 = *(const ushort4*)(Hu + (size_t)s0*256 + lane*4);
        ushort4 h1 = *(const ushort4*)(Hu + (size_t)s1*256 + lane*4);
        ushort4 h2 = *(const ushort4*)(Hu + (size_t)s2*256 + lane*4);
        ushort4 h3 = *(const ushort4*)(Hu + (size_t)s3*256 + lane*4);
        float x0 = als[(size_t)s0*4 + h] + aldv;
        float x1 = als[(size_t)s1*4 + h] + aldv;
        float x2 = als[(size_t)s2*4 + h] + aldv;
        float x3 = als[(size_t)s3*4 + h] + aldv;
        float e0 = __expf(x0 > 0.f ? x0 : 0.2f*x0) * inv;
        float e1 = __expf(x1 > 0.f ? x1 : 0.2f*x1) * inv;
        float e2 = __expf(x2 > 0.f ? x2 : 0.2f*x2) * inv;
        float e3 = __expf(x3 > 0.f ? x3 : 0.2f*x3) * inv;
        a0 += e0*us2f(h0.x) + e1*us2f(h1.x) + e2*us2f(h2.x) + e3*us2f(h3.x);
        a1 += e0*us2f(h0.y) + e1*us2f(h1.y) + e2*us2f(h2.y) + e3*us2f(h3.y);
        a2 += e0*us2f(h0.z) + e1*us2f(h1.z) + e2*us2f(h2.z) + e3*us2f(h3.z);
        a3 += e0*us2f(h0.w) + e1*us2f(h1.w) + e2*us2f(h2.w) + e3*us2f(h3.w);
    }
    for (; i < end; i++){
        int s = srcs[i];
        ushort4 hv = *(const ushort4*)(Hu + (size_t)s*256 + lane*4);
        float x = als[(size_t)s*4 + h] + aldv;
        float e = __expf(x > 0.f ? x : 0.2f*x) * inv;
        a0 += e*us2f(hv.x); a1 += e*us2f(hv.y); a2 += e*us2f(hv.z); a3 += e*us2f(hv.w);
    }
    float* ap = g.acc[gi] + (size_t)w*256 + lane*4;
    if (mode == 0){
        ap[0] = a0; ap[1] = a1; ap[2] = a2; ap[3] = a3;
    } else {
        const float* bp = g.bias[gi] + lane*4;
        float v0 = (ap[0] + a0)*0.5f + bp[0];
        float v1 = (ap[1] + a1)*0.5f + bp[1];
        float v2 = (ap[2] + a2)*0.5f + bp[2];
        float v3 = (ap[3] + a3)*0.5f + bp[3];
        v0 = v0 > 0.f ? v0 : (__expf(v0) - 1.f);
        v1 = v1 > 0.f ? v1 : (__expf(v1) - 1.f);
        v2 = v2 > 0.f ? v2 : (__expf(v2) - 1.f);
        v3 = v3 > 0.f ? v3 : (__expf(v3) - 1.f);
        ushort4 st; st.x = f2bu(v0); st.y = f2bu(v1); st.z = f2bu(v2); st.w = f2bu(v3);
        *(ushort4*)(g.x2b[gi] + (size_t)w*256 + lane*4) = st;
    }
}

// mode 0: raw sums. mode 1: mean+bias + L2-normalize + final store (fused finalize).
__global__ void gat_gather64_b(G3Args g, int mode, void* __restrict__ out,
                               const int* __restrict__ flag){
    int gw = blockIdx.x * 4 + (threadIdx.x >> 6);
    int nd0 = g.nd[0], nd01 = nd0 + g.nd[1], tot = nd01 + g.nd[2];
    if (gw >= tot) return;
    int gi, w;
    if (gw < nd0){ gi = 0; w = gw; }
    else if (gw < nd01){ gi = 1; w = gw - nd0; }
    else { gi = 2; w = gw - nd01; }
    int lane = threadIdx.x & 63;
    const float* als = g.als[gi];
    const unsigned short* srcs = g.srcs[gi];
    float aldv = g.ald[gi][w];
    int beg = g.off[gi][w], end = g.off[gi][w+1];
    float den = 0.f;
    for (int i = beg + lane; i < end; i += 64){
        float a = als[srcs[i]] + aldv;
        den += __expf(a > 0.f ? a : 0.2f*a);
    }
    #pragma unroll
    for (int mk = 32; mk > 0; mk >>= 1) den += __shfl_xor(den, mk, 64);
    float inv = 1.0f / (den + 1e-16f);
    float a0 = 0.f;
    const unsigned short* Hu = g.hs[gi];
    int i = beg;
    for (; i + 4 <= end; i += 4){
        int s0 = srcs[i], s1 = srcs[i+1], s2 = srcs[i+2], s3 = srcs[i+3];
        unsigned short h0 = Hu[(size_t)s0*64 + lane];
        unsigned short h1 = Hu[(size_t)s1*64 + lane];
        unsigned short h2 = Hu[(size_t)s2*64 + lane];
        unsigned short h3 = Hu[(size_t)s3*64 + lane];
        float x0 = als[s0] + aldv, x1 = als[s1] + aldv;
        float x2 = als[s2] + aldv, x3 = als[s3] + aldv;
        float e0 = __expf(x0 > 0.f ? x0 : 0.2f*x0) * inv;
        float e1 = __expf(x1 > 0.f ? x1 : 0.2f*x1) * inv;
        float e2 = __expf(x2 > 0.f ? x2 : 0.2f*x2) * inv;
        float e3 = __expf(x3 > 0.f ? x3 : 0.2f*x3) * inv;
        a0 += e0*us2f(h0) + e1*us2f(h1) + e2*us2f(h2) + e3*us2f(h3);
    }
    for (; i < end; i++){
        int s = srcs[i];
        float x = als[s] + aldv;
        float e = __expf(x > 0.f ? x : 0.2f*x) * inv;
        a0 += e * us2f(Hu[(size_t)s*64 + lane]);
    }
    if (mode == 0){
        g.acc[gi][(size_t)w*64 + lane] = a0;
    } else {
        float prev = g.acc[gi][(size_t)w*64 + lane];
        float v = (prev + a0)*0.5f + g.bias[gi][lane];
        float ss = v * v;
        #pragma unroll
        for (int mk = 32; mk > 0; mk >>= 1) ss += __shfl_xor(ss, mk, 64);
        float nrm = sqrtf(ss);
        nrm = nrm > 1e-12f ? nrm : 1e-12f;
        float rv = v / nrm;
        size_t idx = g.outOff[gi] + (size_t)w*64 + lane;
        if (*flag) ((float*)out)[idx] = rv;
        else       ((bf16*)out)[idx] = __float2bfloat16(rv);
    }
}

// ---------- host ----------
extern "C" void kernel_launch(void* const* d_in, const int* in_sizes, int n_in,
                              void* d_out, int out_size, void* d_ws, size_t ws_size,
                              hipStream_t stream){
    const void* x[3] = {d_in[0], d_in[1], d_in[2]};
    const int Nt[3] = {NCIRC, NMI, NDIS};
    const int* ep[6]; int Ecnt[6];
    for (int r = 0; r < 6; r++){ ep[r] = (const int*)d_in[3 + r]; Ecnt[r] = in_sizes[3 + r] / 2; }
    const void* W1  = d_in[9];
    const void* as1 = d_in[10];
    const void* ad1 = d_in[11];
    const void* b1  = d_in[12];
    const void* W2  = d_in[13];
    const void* as2 = d_in[14];
    const void* ad2 = d_in[15];
    const void* b2  = d_in[16];

    const int rs[6] = {0, 1, 0, 1, 2, 2};
    const int rd[6] = {1, 2, 2, 0, 1, 0};
    const int srel[3][2] = {{0, 2}, {1, 3}, {4, 5}};
    const int drel[3][2] = {{3, 5}, {0, 4}, {1, 2}};
    const int accRow[3] = {0, NCIRC, NCIRC + NMI};
    const int grp[2][3] = {{0, 1, 3}, {2, 4, 5}};      // disjoint dst types per group

    // ---- workspace layout (~171 MB of 256 MiB) ----
    float* ws    = (float*)d_ws;
    int*   FLAG  = (int*)ws;
    float* WA1S  = ws + 16;
    float* WA1D  = WA1S + 6*512;
    float* WA2S  = WA1D + 6*512;
    float* WA2D  = WA2S + 6*256;
    float* BIAS1 = WA2D + 6*256;                        // 3*256
    float* BIAS2 = BIAS1 + 768;                         // 3*64
    float* ALB   = BIAS2 + 192;                         // 1,008,000
    float* R1    = ALB + 1008000;                       // 16,128,000 (HS1 bf16 | ACC2+HS2)
    float* ACC1  = R1 + 16128000;                       // 16,128,000 (mode-0 raw sums)
    unsigned short* X2Bu = (unsigned short*)(ACC1 + 16128000);  // 16,128,000 ushort (bf16 X2)
    bf16*  W1T   = (bf16*)(X2Bu + 16128000);
    bf16*  W2T   = W1T + 6*256*128;
    int*   CNT   = (int*)(W2T + 6*64*256);
    int*   OFF   = CNT + 6*OFFSTR;
    unsigned short* SRCS = (unsigned short*)(OFF + 6*OFFSTR);   // 2,000,000 ushort
    unsigned short* HS1u = (unsigned short*)R1;
    float* ACC2  = R1;
    unsigned short* HS2u = (unsigned short*)(R1 + 4032000);

    int eOff[6]; int acc_e = 0;
    for (int r = 0; r < 6; r++){ eOff[r] = acc_e; acc_e += Ecnt[r]; }
    unsigned long long hs1off[6], hs2off[6];
    { unsigned long long o1 = 0, o2 = 0;
      for (int r = 0; r < 6; r++){ hs1off[r] = o1; o1 += (unsigned long long)Nt[rs[r]]*256;
                                   hs2off[r] = o2; o2 += (unsigned long long)Nt[rs[r]]*64; } }
    float *AL1S[6], *AL1D[6], *AL2S[6], *AL2D[6];
    { size_t o = 0;
      for (int r = 0; r < 6; r++){ AL1S[r] = ALB + o; o += (size_t)Nt[rs[r]]*4; }
      for (int r = 0; r < 6; r++){ AL1D[r] = ALB + o; o += (size_t)Nt[rd[r]]*4; }
      size_t o2 = 0;
      for (int r = 0; r < 6; r++){ AL2S[r] = ALB + o2; o2 += (size_t)Nt[rs[r]]; }
      for (int r = 0; r < 6; r++){ AL2D[r] = ALB + o2; o2 += (size_t)Nt[rd[r]]; } }

    int maxE = 0; for (int r = 0; r < 6; r++) if (Ecnt[r] > maxE) maxE = Ecnt[r];

    hipMemsetAsync(FLAG, 0, sizeof(int), stream);
    detect_dtype<<<1, 256, 0, stream>>>((const unsigned short*)d_in[0], FLAG);

    transpose_w<<<cdiv(6LL*128*256, 256), 256, 0, stream>>>(W1, FLAG, W1T, 128, 256, 6);
    transpose_w<<<cdiv(6LL*256*64, 256), 256, 0, stream>>>(W2, FLAG, W2T, 256, 64, 6);
    fold_bias<<<3, 256, 0, stream>>>(b1, b2, FLAG, BIAS1, BIAS2);

    // ---- CSR build ----
    CsrArgs ca;
    for (int r = 0; r < 6; r++){
        ca.src[r] = ep[r]; ca.dst[r] = ep[r] + Ecnt[r];
        ca.ecnt[r] = Ecnt[r]; ca.eoff[r] = eOff[r]; ca.nd[r] = Nt[rd[r]];
    }
    hipMemsetAsync(CNT, 0, (size_t)6*OFFSTR*sizeof(int), stream);
    csr_count_all<<<dim3(cdiv(maxE, 256), 6), 256, 0, stream>>>(ca, CNT);
    csr_scan_all<<<6, 1024, 0, stream>>>(ca, CNT, OFF);
    hipMemsetAsync(CNT, 0, (size_t)6*OFFSTR*sizeof(int), stream);
    csr_fill_all<<<dim3(cdiv(maxE, 256), 6), 256, 0, stream>>>(ca, OFF, CNT, SRCS);

    compute_wa1_all<<<6, 512, 0, stream>>>(W1, as1, ad1, FLAG, WA1S, WA1D);
    compute_wa2_all<<<6, 256, 0, stream>>>(W2, as2, ad2, FLAG, WA2S, WA2D);

    // ===== layer 1 =====
    Al1Args a1;
    for (int t = 0; t < 3; t++){
        a1.x[t] = x[t]; a1.nt[t] = Nt[t];
        for (int j = 0; j < 2; j++){
            a1.wa[t][j]   = WA1S + srel[t][j]*512;  a1.out[t][j]   = AL1S[srel[t][j]];
            a1.wa[t][j+2] = WA1D + drel[t][j]*512;  a1.out[t][j+2] = AL1D[drel[t][j]];
        }
    }
    al1_all<<<dim3(cdiv(NCIRC, 256), 3), 256, 0, stream>>>(a1, FLAG);

    GemmArgs g1;
    int totBlk = 0;
    for (int r = 0; r < 6; r++){
        g1.A[r] = x[rs[r]]; g1.bOff[r] = (unsigned long long)r*256*128;
        g1.cOff[r] = hs1off[r]; g1.M[r] = Nt[rs[r]];
        g1.nblk[r] = cdiv(Nt[rs[r]], 64); totBlk += g1.nblk[r];
    }
    gemm_mfma_b<<<dim3(4, totBlk), 256, 0, stream>>>(g1, 2, W1T, FLAG, (bf16*)HS1u, 256, 128);

    for (int g = 0; g < 2; g++){
        G3Args ga; int tot = 0;
        for (int k = 0; k < 3; k++){
            int r = grp[g][k];
            int t = rd[r];
            ga.srcs[k] = SRCS + eOff[r]; ga.off[k] = OFF + r*OFFSTR;
            ga.als[k] = AL1S[r]; ga.ald[k] = AL1D[r];
            ga.hs[k] = HS1u + hs1off[r];
            ga.acc[k] = ACC1 + (size_t)accRow[t]*256;
            ga.bias[k] = BIAS1 + t*256;
            ga.x2b[k] = X2Bu + (size_t)accRow[t]*256;
            ga.outOff[k] = 0;
            ga.nd[k] = Nt[t];
            tot += Nt[t];
        }
        gat_gather256_b<<<cdiv(tot, 4), 256, 0, stream>>>(ga, g);
    }

    // ===== layer 2 =====
    Al2Args a2;
    for (int t = 0; t < 3; t++){
        a2.x[t] = X2Bu + (size_t)accRow[t]*256; a2.nt[t] = Nt[t];
        for (int j = 0; j < 2; j++){
            a2.wa[t][j]   = WA2S + srel[t][j]*256;  a2.out[t][j]   = AL2S[srel[t][j]];
            a2.wa[t][j+2] = WA2D + drel[t][j]*256;  a2.out[t][j+2] = AL2D[drel[t][j]];
        }
    }
    al2_all<<<dim3(cdiv(NCIRC, 256), 3), 256, 0, stream>>>(a2);

    GemmArgs g2;
    totBlk = 0;
    for (int r = 0; r < 6; r++){
        g2.A[r] = X2Bu + (size_t)accRow[rs[r]]*256; g2.bOff[r] = (unsigned long long)r*64*256;
        g2.cOff[r] = hs2off[r]; g2.M[r] = Nt[rs[r]];
        g2.nblk[r] = cdiv(Nt[rs[r]], 64); totBlk += g2.nblk[r];
    }
    gemm_mfma_b<<<dim3(1, totBlk), 256, 0, stream>>>(g2, 0, W2T, FLAG, (bf16*)HS2u, 64, 256);

    for (int g = 0; g < 2; g++){
        G3Args ga; int tot = 0;
        for (int k = 0; k < 3; k++){
            int r = grp[g][k];
            int t = rd[r];
            ga.srcs[k] = SRCS + eOff[r]; ga.off[k] = OFF + r*OFFSTR;
            ga.als[k] = AL2S[r]; ga.ald[k] = AL2D[r];
            ga.hs[k] = HS2u + hs2off[r];
            ga.acc[k] = ACC2 + (size_t)accRow[t]*64;
            ga.bias[k] = BIAS2 + t*64;
            ga.x2b[k] = nullptr;
            ga.outOff[k] = (unsigned long long)accRow[t]*64;
            ga.nd[k] = Nt[t];
            tot += Nt[t];
        }
        gat_gather64_b<<<cdiv(tot, 4), 256, 0, stream>>>(ga, g, d_out, FLAG);
    }
}

// Round 7
// 713.717 us; speedup vs baseline: 12.3800x; 1.0586x over previous
//
#include <hip/hip_runtime.h>
#include <hip/hip_bf16.h>
#include <math.h>

#define NCIRC 40000
#define NMI   15000
#define NDIS  8000
#define NTOT  (NCIRC + NMI + NDIS)
#define OFFSTR 40064

typedef __hip_bfloat16 bf16;
typedef __attribute__((ext_vector_type(8))) short short8;
typedef __attribute__((ext_vector_type(4))) float f32x4;
typedef __attribute__((ext_vector_type(8))) unsigned short us8v;

static __device__ __forceinline__ float us2f(unsigned short u){ return __uint_as_float(((unsigned)u) << 16); }
static __device__ __forceinline__ unsigned short f2bu(float v){
    bf16 t = __float2bfloat16(v);
    return *reinterpret_cast<unsigned short*>(&t);
}
static __device__ __forceinline__ float ldx(const void* p, size_t i, int f32){
    return f32 ? ((const float*)p)[i] : __bfloat162float(((const bf16*)p)[i]);
}
static inline unsigned cdiv(long long a, long long b){ return (unsigned)((a + b - 1) / b); }

// ---------- arg structs ----------
struct CsrArgs {
    const int* src[6]; const int* dst[6];
    int ecnt[6]; int eoff[6]; int nd[6];
};
struct Al1Args { const void* x[3]; const float* wa[3][4]; float* out[3][4]; int nt[3]; };
struct Al2Args { const unsigned short* x[3]; const float* wa[3][4]; float* out[3][4]; int nt[3]; };
struct GemmArgs { const void* A[6]; unsigned long long bOff[6]; unsigned long long cOff[6];
                  int M[6]; int nblk[6]; };
// per dst type t, its two incoming relations a=0,1
struct GatArgs {
    const unsigned short* srcs[3][2]; const int* off[3][2];
    const float* als[3][2]; const float* ald[3][2];
    const unsigned short* hs[3][2];
};

// ---------- dtype detection ----------
__global__ void detect_dtype(const unsigned short* __restrict__ u, int* __restrict__ flag){
    int bad = 0;
    for (int i = threadIdx.x; i < 4096; i += 256){
        int e = (u[i] >> 7) & 0xFF;
        if (e >= 0x90) bad = 1;
    }
    if (bad) atomicOr(flag, 1);
}

// ---------- CSR build ----------
__global__ void csr_count_all(CsrArgs a, int* __restrict__ cnt){
    int r = blockIdx.y;
    int e = blockIdx.x * 256 + threadIdx.x;
    if (e < a.ecnt[r]) atomicAdd(&cnt[r*OFFSTR + a.dst[r][e]], 1);
}

__global__ void csr_scan_all(CsrArgs a, const int* __restrict__ cnt, int* __restrict__ off){
    int r = blockIdx.x;
    int N = a.nd[r];
    const int* c = cnt + r*OFFSTR;
    int* o = off + r*OFFSTR;
    __shared__ int wsum[16];
    __shared__ int base;
    int tid = threadIdx.x, lane = tid & 63, wv = tid >> 6;
    if (tid == 0) base = 0;
    __syncthreads();
    for (int c0 = 0; c0 < N; c0 += 1024){
        int i = c0 + tid;
        int x = (i < N) ? c[i] : 0;
        #pragma unroll
        for (int d = 1; d < 64; d <<= 1){
            int y = __shfl_up(x, d, 64);
            if (lane >= d) x += y;
        }
        if (lane == 63) wsum[wv] = x;
        __syncthreads();
        if (tid == 0){
            int s = 0;
            #pragma unroll
            for (int k = 0; k < 16; k++){ s += wsum[k]; wsum[k] = s; }
        }
        __syncthreads();
        int woff = (wv == 0) ? 0 : wsum[wv - 1];
        if (i < N) o[i + 1] = base + woff + x;
        int total = wsum[15];
        __syncthreads();
        if (tid == 0) base += total;
        __syncthreads();
    }
    if (tid == 0) o[0] = 0;
}

__global__ void csr_fill_all(CsrArgs a, const int* __restrict__ off,
                             int* __restrict__ pos, unsigned short* __restrict__ srcs){
    int r = blockIdx.y;
    int e = blockIdx.x * 256 + threadIdx.x;
    if (e >= a.ecnt[r]) return;
    int d = a.dst[r][e];
    int p = atomicAdd(&pos[r*OFFSTR + d], 1);
    srcs[a.eoff[r] + off[r*OFFSTR + d] + p] = (unsigned short)a.src[r][e];
}

// ---------- weight transpose ----------
__global__ void transpose_w(const void* __restrict__ W, const int* __restrict__ flag,
                            bf16* __restrict__ WT, int Kd, int Nd, int nrel){
    int f32 = *flag;
    long long idx = (long long)blockIdx.x * 256 + threadIdx.x;
    long long tot = (long long)nrel * Kd * Nd;
    if (idx >= tot) return;
    int per = Kd * Nd;
    int r = (int)(idx / per);
    int rem = (int)(idx % per);
    int n = rem / Kd, k = rem % Kd;
    float v = ldx(W, (size_t)r*per + (size_t)k*Nd + n, f32);
    WT[idx] = __float2bfloat16(v);
}

// ---------- weight folding ----------
__global__ void compute_wa1_all(const void* __restrict__ W1, const void* __restrict__ as1,
                                const void* __restrict__ ad1, const int* __restrict__ flag,
                                float* __restrict__ wa_s, float* __restrict__ wa_d){
    int f32 = *flag;
    int r = blockIdx.x;
    int t = threadIdx.x;
    int f = t >> 2, h = t & 3;
    size_t wb = (size_t)r*128*256 + (size_t)f*256 + h*64;
    size_t ab = (size_t)r*256 + h*64;
    float ss = 0.f, sd = 0.f;
    for (int c = 0; c < 64; c++){
        float w = ldx(W1, wb + c, f32);
        ss += w * ldx(as1, ab + c, f32);
        sd += w * ldx(ad1, ab + c, f32);
    }
    wa_s[r*512 + t] = ss; wa_d[r*512 + t] = sd;
}

__global__ void compute_wa2_all(const void* __restrict__ W2, const void* __restrict__ as2,
                                const void* __restrict__ ad2, const int* __restrict__ flag,
                                float* __restrict__ wa_s, float* __restrict__ wa_d){
    int f32 = *flag;
    int r = blockIdx.x;
    int f = threadIdx.x;
    size_t wb = (size_t)r*256*64 + (size_t)f*64;
    float ss = 0.f, sd = 0.f;
    for (int c = 0; c < 64; c++){
        float w = ldx(W2, wb + c, f32);
        ss += w * ldx(as2, (size_t)r*64 + c, f32);
        sd += w * ldx(ad2, (size_t)r*64 + c, f32);
    }
    wa_s[r*256 + f] = ss; wa_d[r*256 + f] = sd;
}

// ---------- per-dst-type fused bias ----------
__global__ void fold_bias(const void* __restrict__ b1, const void* __restrict__ b2,
                          const int* __restrict__ flag,
                          float* __restrict__ BIAS1, float* __restrict__ BIAS2){
    const int relA[3] = {3, 0, 1};
    const int relB[3] = {5, 4, 2};
    int t = blockIdx.x, c = threadIdx.x, f32 = *flag;
    BIAS1[t*256 + c] = 0.5f*(ldx(b1, relA[t]*256 + c, f32) + ldx(b1, relB[t]*256 + c, f32));
    if (c < 64)
        BIAS2[t*64 + c] = 0.5f*(ldx(b2, relA[t]*64 + c, f32) + ldx(b2, relB[t]*64 + c, f32));
}

// ---------- layer-1 logits ----------
__global__ void al1_all(Al1Args a, const int* __restrict__ flag){
    int t = blockIdx.y;
    int N = a.nt[t];
    if ((int)(blockIdx.x * 256) >= N) return;
    __shared__ float swa[4][512];
    for (int i = threadIdx.x; i < 2048; i += 256) swa[i >> 9][i & 511] = a.wa[t][i >> 9][i & 511];
    __syncthreads();
    int n = blockIdx.x * 256 + threadIdx.x;
    if (n >= N) return;
    int f32 = *flag;
    float s[4][4] = {};
    if (f32){
        const float* xr = (const float*)a.x[t] + (size_t)n*128;
        for (int f = 0; f < 128; f++){
            float v = xr[f];
            #pragma unroll
            for (int j = 0; j < 4; j++){
                s[j][0] += v*swa[j][f*4+0]; s[j][1] += v*swa[j][f*4+1];
                s[j][2] += v*swa[j][f*4+2]; s[j][3] += v*swa[j][f*4+3];
            }
        }
    } else {
        const unsigned short* xr = (const unsigned short*)a.x[t] + (size_t)n*128;
        for (int f0 = 0; f0 < 128; f0 += 8){
            us8v v8 = *(const us8v*)(xr + f0);
            #pragma unroll
            for (int jj = 0; jj < 8; jj++){
                float v = us2f(v8[jj]); int f = f0 + jj;
                #pragma unroll
                for (int j = 0; j < 4; j++){
                    s[j][0] += v*swa[j][f*4+0]; s[j][1] += v*swa[j][f*4+1];
                    s[j][2] += v*swa[j][f*4+2]; s[j][3] += v*swa[j][f*4+3];
                }
            }
        }
    }
    #pragma unroll
    for (int j = 0; j < 4; j++)
        *(float4*)(a.out[t][j] + (size_t)n*4) = make_float4(s[j][0], s[j][1], s[j][2], s[j][3]);
}

// ---------- layer-2 logits (bf16 X2) ----------
__global__ void al2_all(Al2Args a){
    int t = blockIdx.y;
    int N = a.nt[t];
    if ((int)(blockIdx.x * 256) >= N) return;
    __shared__ float swa[4][256];
    for (int i = threadIdx.x; i < 1024; i += 256) swa[i >> 8][i & 255] = a.wa[t][i >> 8][i & 255];
    __syncthreads();
    int n = blockIdx.x * 256 + threadIdx.x;
    if (n >= N) return;
    const unsigned short* xr = a.x[t] + (size_t)n*256;
    float s0 = 0.f, s1 = 0.f, s2 = 0.f, s3 = 0.f;
    for (int f0 = 0; f0 < 256; f0 += 8){
        us8v v8 = *(const us8v*)(xr + f0);
        #pragma unroll
        for (int jj = 0; jj < 8; jj++){
            float v = us2f(v8[jj]); int f = f0 + jj;
            s0 += v*swa[0][f]; s1 += v*swa[1][f]; s2 += v*swa[2][f]; s3 += v*swa[3][f];
        }
    }
    a.out[t][0][n] = s0; a.out[t][1][n] = s1; a.out[t][2][n] = s2; a.out[t][3][n] = s3;
}

// ---------- packed MFMA GEMM ----------
__global__ void gemm_mfma_b(GemmArgs ga, int amode, const bf16* __restrict__ WT,
                            const int* __restrict__ flag, bf16* __restrict__ Cb,
                            int N, int K){
    int y = blockIdx.y, r = 0;
    while (r < 5 && y >= ga.nblk[r]){ y -= ga.nblk[r]; r++; }
    int M = ga.M[r];
    int m0 = y * 64, n0 = blockIdx.x * 64;
    int af32 = (amode == 2) ? *flag : amode;
    const void* A = ga.A[r];
    const unsigned short* WTu = (const unsigned short*)WT + ga.bOff[r];
    bf16* C = Cb + ga.cOff[r];
    __shared__ unsigned short As[64][40];
    __shared__ unsigned short Bs[64][40];
    int tid = threadIdx.x;
    int w = tid >> 6, lane = tid & 63;
    int quad = lane >> 4, l16 = lane & 15;
    int srow = tid >> 2, skc = (tid & 3) * 8;
    f32x4 acc[4] = {};
    for (int k0 = 0; k0 < K; k0 += 32){
        {
            int gr = m0 + srow;
            us8v av;
            if (gr < M){
                if (af32){
                    const float* ap = (const float*)A + (size_t)gr*K + k0 + skc;
                    #pragma unroll
                    for (int j = 0; j < 8; j++) av[j] = f2bu(ap[j]);
                } else {
                    av = *(const us8v*)((const unsigned short*)A + (size_t)gr*K + k0 + skc);
                }
            } else {
                #pragma unroll
                for (int j = 0; j < 8; j++) av[j] = 0;
            }
            *(us8v*)&As[srow][skc] = av;
        }
        *(us8v*)&Bs[srow][skc] = *(const us8v*)(WTu + (size_t)(n0 + srow)*K + k0 + skc);
        __syncthreads();
        short8 af = *(const short8*)&As[w*16 + l16][quad*8];
        #pragma unroll
        for (int c = 0; c < 4; c++){
            short8 bf = *(const short8*)&Bs[c*16 + l16][quad*8];
            acc[c] = __builtin_amdgcn_mfma_f32_16x16x32_bf16(af, bf, acc[c], 0, 0, 0);
        }
        __syncthreads();
    }
    #pragma unroll
    for (int c = 0; c < 4; c++){
        #pragma unroll
        for (int i = 0; i < 4; i++){
            int m = m0 + w*16 + quad*4 + i;
            if (m < M) C[(size_t)m*N + n0 + c*16 + l16] = __float2bfloat16(acc[c][i]);
        }
    }
}

// ---------- layer-1 gather: one wave per dst node, BOTH relations, fused ELU epilogue.
// Half-wave row layout: 32 lanes x ushort8 (16B) cover the 512B row; 2 edges in flight.
__global__ void gat_l1(GatArgs g, const float* __restrict__ BIAS1,
                       unsigned short* __restrict__ X2B){
    int gw = blockIdx.x * 4 + (threadIdx.x >> 6);
    if (gw >= NTOT) return;
    int t, w;
    if (gw < NCIRC){ t = 0; w = gw; }
    else if (gw < NCIRC + NMI){ t = 1; w = gw - NCIRC; }
    else { t = 2; w = gw - NCIRC - NMI; }
    int lane = threadIdx.x & 63;
    int hw = lane >> 5, l32 = lane & 31;
    int h = l32 >> 3;
    float facc[8] = {0.f,0.f,0.f,0.f,0.f,0.f,0.f,0.f};
    #pragma unroll
    for (int a = 0; a < 2; a++){
        const float* als = g.als[t][a];
        const unsigned short* srcs = g.srcs[t][a];
        const unsigned short* Hu = g.hs[t][a];
        float4 ald4 = *(const float4*)(g.ald[t][a] + (size_t)w*4);
        int beg = g.off[t][a][w], end = g.off[t][a][w+1];
        // pass 1: per-relation softmax denominators
        float d0 = 0.f, d1 = 0.f, d2 = 0.f, d3 = 0.f;
        for (int i = beg + lane; i < end; i += 64){
            int s = srcs[i];
            float4 a4 = *(const float4*)(als + (size_t)s*4);
            float v;
            v = a4.x + ald4.x; d0 += __expf(v > 0.f ? v : 0.2f*v);
            v = a4.y + ald4.y; d1 += __expf(v > 0.f ? v : 0.2f*v);
            v = a4.z + ald4.z; d2 += __expf(v > 0.f ? v : 0.2f*v);
            v = a4.w + ald4.w; d3 += __expf(v > 0.f ? v : 0.2f*v);
        }
        #pragma unroll
        for (int mk = 32; mk > 0; mk >>= 1){
            d0 += __shfl_xor(d0, mk, 64); d1 += __shfl_xor(d1, mk, 64);
            d2 += __shfl_xor(d2, mk, 64); d3 += __shfl_xor(d3, mk, 64);
        }
        float invh = 1.0f / (((h < 2) ? (h == 0 ? d0 : d1) : (h == 2 ? d2 : d3)) + 1e-16f);
        float aldv = (h < 2) ? (h == 0 ? ald4.x : ald4.y) : (h == 2 ? ald4.z : ald4.w);
        // pass 2: half-wave per edge, ushort8 loads, x4 edges unrolled
        int i = beg + hw;
        for (; i + 6 < end; i += 8){
            int s0 = srcs[i], s1 = srcs[i+2], s2 = srcs[i+4], s3 = srcs[i+6];
            us8v v0 = *(const us8v*)(Hu + (size_t)s0*256 + l32*8);
            us8v v1 = *(const us8v*)(Hu + (size_t)s1*256 + l32*8);
            us8v v2 = *(const us8v*)(Hu + (size_t)s2*256 + l32*8);
            us8v v3 = *(const us8v*)(Hu + (size_t)s3*256 + l32*8);
            float x0 = als[(size_t)s0*4 + h] + aldv;
            float x1 = als[(size_t)s1*4 + h] + aldv;
            float x2 = als[(size_t)s2*4 + h] + aldv;
            float x3 = als[(size_t)s3*4 + h] + aldv;
            float e0 = __expf(x0 > 0.f ? x0 : 0.2f*x0) * invh;
            float e1 = __expf(x1 > 0.f ? x1 : 0.2f*x1) * invh;
            float e2 = __expf(x2 > 0.f ? x2 : 0.2f*x2) * invh;
            float e3 = __expf(x3 > 0.f ? x3 : 0.2f*x3) * invh;
            #pragma unroll
            for (int j = 0; j < 8; j++)
                facc[j] += e0*us2f(v0[j]) + e1*us2f(v1[j]) + e2*us2f(v2[j]) + e3*us2f(v3[j]);
        }
        for (; i < end; i += 2){
            int s = srcs[i];
            us8v v = *(const us8v*)(Hu + (size_t)s*256 + l32*8);
            float x = als[(size_t)s*4 + h] + aldv;
            float e = __expf(x > 0.f ? x : 0.2f*x) * invh;
            #pragma unroll
            for (int j = 0; j < 8; j++) facc[j] += e*us2f(v[j]);
        }
    }
    // combine the two half-waves
    #pragma unroll
    for (int j = 0; j < 8; j++) facc[j] += __shfl_xor(facc[j], 32, 64);
    if (hw == 0){
        const float* bp = BIAS1 + t*256 + l32*8;
        us8v st;
        #pragma unroll
        for (int j = 0; j < 8; j++){
            float v = facc[j]*0.5f + bp[j];
            v = v > 0.f ? v : (__expf(v) - 1.f);
            st[j] = f2bu(v);
        }
        *(us8v*)(X2B + (size_t)gw*256 + l32*8) = st;
    }
}

// ---------- layer-2 gather: one wave per dst node, BOTH relations, fused finalize.
// Quarter-wave row layout: 16 lanes x ushort4 (8B) cover the 128B row; 4 edges in flight.
__global__ void gat_l2(GatArgs g, const float* __restrict__ BIAS2,
                       void* __restrict__ out, const int* __restrict__ flag){
    int gw = blockIdx.x * 4 + (threadIdx.x >> 6);
    if (gw >= NTOT) return;
    int t, w;
    if (gw < NCIRC){ t = 0; w = gw; }
    else if (gw < NCIRC + NMI){ t = 1; w = gw - NCIRC; }
    else { t = 2; w = gw - NCIRC - NMI; }
    int lane = threadIdx.x & 63;
    int qw = lane >> 4, l16 = lane & 15;
    float facc[4] = {0.f,0.f,0.f,0.f};
    #pragma unroll
    for (int a = 0; a < 2; a++){
        const float* als = g.als[t][a];
        const unsigned short* srcs = g.srcs[t][a];
        const unsigned short* Hu = g.hs[t][a];
        float aldv = g.ald[t][a][w];
        int beg = g.off[t][a][w], end = g.off[t][a][w+1];
        float den = 0.f;
        for (int i = beg + lane; i < end; i += 64){
            float v = als[srcs[i]] + aldv;
            den += __expf(v > 0.f ? v : 0.2f*v);
        }
        #pragma unroll
        for (int mk = 32; mk > 0; mk >>= 1) den += __shfl_xor(den, mk, 64);
        float inv = 1.0f / (den + 1e-16f);
        int i = beg + qw;
        for (; i + 4 < end; i += 8){
            int s0 = srcs[i], s1 = srcs[i+4];
            ushort4 v0 = *(const ushort4*)(Hu + (size_t)s0*64 + l16*4);
            ushort4 v1 = *(const ushort4*)(Hu + (size_t)s1*64 + l16*4);
            float x0 = als[s0] + aldv, x1 = als[s1] + aldv;
            float e0 = __expf(x0 > 0.f ? x0 : 0.2f*x0) * inv;
            float e1 = __expf(x1 > 0.f ? x1 : 0.2f*x1) * inv;
            facc[0] += e0*us2f(v0.x) + e1*us2f(v1.x);
            facc[1] += e0*us2f(v0.y) + e1*us2f(v1.y);
            facc[2] += e0*us2f(v0.z) + e1*us2f(v1.z);
            facc[3] += e0*us2f(v0.w) + e1*us2f(v1.w);
        }
        for (; i < end; i += 4){
            int s = srcs[i];
            ushort4 v = *(const ushort4*)(Hu + (size_t)s*64 + l16*4);
            float x = als[s] + aldv;
            float e = __expf(x > 0.f ? x : 0.2f*x) * inv;
            facc[0] += e*us2f(v.x); facc[1] += e*us2f(v.y);
            facc[2] += e*us2f(v.z); facc[3] += e*us2f(v.w);
        }
    }
    #pragma unroll
    for (int j = 0; j < 4; j++){
        facc[j] += __shfl_xor(facc[j], 32, 64);
        facc[j] += __shfl_xor(facc[j], 16, 64);
    }
    const float* bp = BIAS2 + t*64 + l16*4;
    float v0 = facc[0]*0.5f + bp[0];
    float v1 = facc[1]*0.5f + bp[1];
    float v2 = facc[2]*0.5f + bp[2];
    float v3 = facc[3]*0.5f + bp[3];
    float ss = v0*v0 + v1*v1 + v2*v2 + v3*v3;
    #pragma unroll
    for (int mk = 8; mk > 0; mk >>= 1) ss += __shfl_xor(ss, mk, 64);
    float nrm = sqrtf(ss);
    nrm = nrm > 1e-12f ? nrm : 1e-12f;
    float inv_n = 1.0f / nrm;
    if (qw == 0){
        size_t base = (size_t)gw*64 + l16*4;
        if (*flag){
            float4 st = make_float4(v0*inv_n, v1*inv_n, v2*inv_n, v3*inv_n);
            *(float4*)((float*)out + base) = st;
        } else {
            ushort4 st;
            st.x = f2bu(v0*inv_n); st.y = f2bu(v1*inv_n);
            st.z = f2bu(v2*inv_n); st.w = f2bu(v3*inv_n);
            *(ushort4*)((unsigned short*)out + base) = st;
        }
    }
}

// ---------- host ----------
extern "C" void kernel_launch(void* const* d_in, const int* in_sizes, int n_in,
                              void* d_out, int out_size, void* d_ws, size_t ws_size,
                              hipStream_t stream){
    const void* x[3] = {d_in[0], d_in[1], d_in[2]};
    const int Nt[3] = {NCIRC, NMI, NDIS};
    const int* ep[6]; int Ecnt[6];
    for (int r = 0; r < 6; r++){ ep[r] = (const int*)d_in[3 + r]; Ecnt[r] = in_sizes[3 + r] / 2; }
    const void* W1  = d_in[9];
    const void* as1 = d_in[10];
    const void* ad1 = d_in[11];
    const void* b1  = d_in[12];
    const void* W2  = d_in[13];
    const void* as2 = d_in[14];
    const void* ad2 = d_in[15];
    const void* b2  = d_in[16];

    const int rs[6] = {0, 1, 0, 1, 2, 2};
    const int rd[6] = {1, 2, 2, 0, 1, 0};
    const int srel[3][2] = {{0, 2}, {1, 3}, {4, 5}};
    const int drel[3][2] = {{3, 5}, {0, 4}, {1, 2}};

    // ---- workspace layout (~125 MB) ----
    float* ws    = (float*)d_ws;
    int*   FLAG  = (int*)ws;
    float* WA1S  = ws + 16;
    float* WA1D  = WA1S + 6*512;
    float* WA2S  = WA1D + 6*512;
    float* WA2D  = WA2S + 6*256;
    float* BIAS1 = WA2D + 6*256;
    float* BIAS2 = BIAS1 + 768;
    float* ALB   = BIAS2 + 192;                                 // 1,008,000 floats
    unsigned short* HS1u = (unsigned short*)(ALB + 1008000);    // 32,256,000 ushort
    unsigned short* HS2u = HS1u + 32256000;                     //  8,064,000 ushort
    unsigned short* X2Bu = HS2u + 8064000;                      // 16,128,000 ushort
    bf16*  W1T   = (bf16*)(X2Bu + 16128000);                    // 196,608
    bf16*  W2T   = W1T + 6*256*128;                             //  98,304
    int*   CNT   = (int*)(W2T + 6*64*256);
    int*   OFF   = CNT + 6*OFFSTR;
    unsigned short* SRCS = (unsigned short*)(OFF + 6*OFFSTR);   // 2,000,000 ushort

    int eOff[6]; int acc_e = 0;
    for (int r = 0; r < 6; r++){ eOff[r] = acc_e; acc_e += Ecnt[r]; }
    unsigned long long hs1off[6], hs2off[6];
    { unsigned long long o1 = 0, o2 = 0;
      for (int r = 0; r < 6; r++){ hs1off[r] = o1; o1 += (unsigned long long)Nt[rs[r]]*256;
                                   hs2off[r] = o2; o2 += (unsigned long long)Nt[rs[r]]*64; } }
    float *AL1S[6], *AL1D[6], *AL2S[6], *AL2D[6];
    { size_t o = 0;
      for (int r = 0; r < 6; r++){ AL1S[r] = ALB + o; o += (size_t)Nt[rs[r]]*4; }
      for (int r = 0; r < 6; r++){ AL1D[r] = ALB + o; o += (size_t)Nt[rd[r]]*4; }
      size_t o2 = 0;
      for (int r = 0; r < 6; r++){ AL2S[r] = ALB + o2; o2 += (size_t)Nt[rs[r]]; }
      for (int r = 0; r < 6; r++){ AL2D[r] = ALB + o2; o2 += (size_t)Nt[rd[r]]; } }

    int maxE = 0; for (int r = 0; r < 6; r++) if (Ecnt[r] > maxE) maxE = Ecnt[r];

    hipMemsetAsync(FLAG, 0, sizeof(int), stream);
    detect_dtype<<<1, 256, 0, stream>>>((const unsigned short*)d_in[0], FLAG);

    transpose_w<<<cdiv(6LL*128*256, 256), 256, 0, stream>>>(W1, FLAG, W1T, 128, 256, 6);
    transpose_w<<<cdiv(6LL*256*64, 256), 256, 0, stream>>>(W2, FLAG, W2T, 256, 64, 6);
    fold_bias<<<3, 256, 0, stream>>>(b1, b2, FLAG, BIAS1, BIAS2);

    // ---- CSR build ----
    CsrArgs ca;
    for (int r = 0; r < 6; r++){
        ca.src[r] = ep[r]; ca.dst[r] = ep[r] + Ecnt[r];
        ca.ecnt[r] = Ecnt[r]; ca.eoff[r] = eOff[r]; ca.nd[r] = Nt[rd[r]];
    }
    hipMemsetAsync(CNT, 0, (size_t)6*OFFSTR*sizeof(int), stream);
    csr_count_all<<<dim3(cdiv(maxE, 256), 6), 256, 0, stream>>>(ca, CNT);
    csr_scan_all<<<6, 1024, 0, stream>>>(ca, CNT, OFF);
    hipMemsetAsync(CNT, 0, (size_t)6*OFFSTR*sizeof(int), stream);
    csr_fill_all<<<dim3(cdiv(maxE, 256), 6), 256, 0, stream>>>(ca, OFF, CNT, SRCS);

    compute_wa1_all<<<6, 512, 0, stream>>>(W1, as1, ad1, FLAG, WA1S, WA1D);
    compute_wa2_all<<<6, 256, 0, stream>>>(W2, as2, ad2, FLAG, WA2S, WA2D);

    // ===== layer 1 =====
    Al1Args a1;
    for (int t = 0; t < 3; t++){
        a1.x[t] = x[t]; a1.nt[t] = Nt[t];
        for (int j = 0; j < 2; j++){
            a1.wa[t][j]   = WA1S + srel[t][j]*512;  a1.out[t][j]   = AL1S[srel[t][j]];
            a1.wa[t][j+2] = WA1D + drel[t][j]*512;  a1.out[t][j+2] = AL1D[drel[t][j]];
        }
    }
    al1_all<<<dim3(cdiv(NCIRC, 256), 3), 256, 0, stream>>>(a1, FLAG);

    GemmArgs g1;
    int totBlk = 0;
    for (int r = 0; r < 6; r++){
        g1.A[r] = x[rs[r]]; g1.bOff[r] = (unsigned long long)r*256*128;
        g1.cOff[r] = hs1off[r]; g1.M[r] = Nt[rs[r]];
        g1.nblk[r] = cdiv(Nt[rs[r]], 64); totBlk += g1.nblk[r];
    }
    gemm_mfma_b<<<dim3(4, totBlk), 256, 0, stream>>>(g1, 2, W1T, FLAG, (bf16*)HS1u, 256, 128);

    GatArgs gl1;
    for (int t = 0; t < 3; t++)
        for (int a = 0; a < 2; a++){
            int r = drel[t][a];
            gl1.srcs[t][a] = SRCS + eOff[r]; gl1.off[t][a] = OFF + r*OFFSTR;
            gl1.als[t][a] = AL1S[r]; gl1.ald[t][a] = AL1D[r];
            gl1.hs[t][a] = HS1u + hs1off[r];
        }
    gat_l1<<<cdiv(NTOT, 4), 256, 0, stream>>>(gl1, BIAS1, X2Bu);

    // ===== layer 2 =====
    Al2Args a2;
    const int accRow[3] = {0, NCIRC, NCIRC + NMI};
    for (int t = 0; t < 3; t++){
        a2.x[t] = X2Bu + (size_t)accRow[t]*256; a2.nt[t] = Nt[t];
        for (int j = 0; j < 2; j++){
            a2.wa[t][j]   = WA2S + srel[t][j]*256;  a2.out[t][j]   = AL2S[srel[t][j]];
            a2.wa[t][j+2] = WA2D + drel[t][j]*256;  a2.out[t][j+2] = AL2D[drel[t][j]];
        }
    }
    al2_all<<<dim3(cdiv(NCIRC, 256), 3), 256, 0, stream>>>(a2);

    GemmArgs g2;
    totBlk = 0;
    for (int r = 0; r < 6; r++){
        g2.A[r] = X2Bu + (size_t)accRow[rs[r]]*256; g2.bOff[r] = (unsigned long long)r*64*256;
        g2.cOff[r] = hs2off[r]; g2.M[r] = Nt[rs[r]];
        g2.nblk[r] = cdiv(Nt[rs[r]], 64); totBlk += g2.nblk[r];
    }
    gemm_mfma_b<<<dim3(1, totBlk), 256, 0, stream>>>(g2, 0, W2T, FLAG, (bf16*)HS2u, 64, 256);

    GatArgs gl2;
    for (int t = 0; t < 3; t++)
        for (int a = 0; a < 2; a++){
            int r = drel[t][a];
            gl2.srcs[t][a] = SRCS + eOff[r]; gl2.off[t][a] = OFF + r*OFFSTR;
            gl2.als[t][a] = AL2S[r]; gl2.ald[t][a] = AL2D[r];
            gl2.hs[t][a] = HS2u + hs2off[r];
        }
    gat_l2<<<cdiv(NTOT, 4), 256, 0, stream>>>(gl2, BIAS2, d_out, FLAG);
}

// Round 8
// 687.723 us; speedup vs baseline: 12.8480x; 1.0378x over previous
//
#include <hip/hip_runtime.h>
#include <hip/hip_bf16.h>
#include <math.h>

#define NCIRC 40000
#define NMI   15000
#define NDIS  8000
#define NTOT  (NCIRC + NMI + NDIS)
#define OFFSTR 40064

typedef __hip_bfloat16 bf16;
typedef __attribute__((ext_vector_type(8))) short short8;
typedef __attribute__((ext_vector_type(4))) float f32x4;
typedef __attribute__((ext_vector_type(8))) unsigned short us8v;

static __device__ __forceinline__ float us2f(unsigned short u){ return __uint_as_float(((unsigned)u) << 16); }
static __device__ __forceinline__ unsigned short f2bu(float v){
    bf16 t = __float2bfloat16(v);
    return *reinterpret_cast<unsigned short*>(&t);
}
static __device__ __forceinline__ float ldx(const void* p, size_t i, int f32){
    return f32 ? ((const float*)p)[i] : __bfloat162float(((const bf16*)p)[i]);
}
static inline unsigned cdiv(long long a, long long b){ return (unsigned)((a + b - 1) / b); }

// ---------- arg structs ----------
struct CsrArgs {
    const int* src[6]; const int* dst[6];
    int ecnt[6]; int eoff[6]; int nd[6];
};
struct Al1Args { const void* x[3]; const float* wa[3][4]; float* out[3][4]; int nt[3]; };
struct Al2Args { const unsigned short* x[3]; const float* wa[3][4]; float* out[3][4]; int nt[3]; };
struct GemmArgs { const void* A[6]; unsigned long long bOff[6]; unsigned long long cOff[6];
                  int M[6]; int nblk[6]; };
struct GatArgs {
    const unsigned short* srcs[3][2]; const int* off[3][2];
    const float* als[3][2]; const float* ald[3][2];
    const unsigned short* hs[3][2];
};
struct P1Args {     // transpose + wa-fold + bias + csr_count
    CsrArgs ca;
    const void *W1, *as1, *ad1, *W2, *as2, *ad2, *b1, *b2;
    float *WA1S, *WA1D, *WA2S, *WA2D, *BIAS1, *BIAS2;
    bf16 *W1T, *W2T;
    int *CNT;
    int eTw1, eTw2, eWa1, eWa2, eBias;   // cumulative block-range ends
    int nbCnt[6];
};
struct P2Args {     // csr_fill + gemm L1 + al1
    CsrArgs ca;
    const int* OFF; int* POS; unsigned short* SRCS;
    GemmArgs g1;
    Al1Args a1;
    int eFill, eGemm;
    int nbCnt[6];
    int nbAl[3];
};
struct P3Args {     // al2 + gemm L2
    Al2Args a2;
    GemmArgs g2;
    int eAl2;
    int nbAl[3];
};

// ---------- dtype detection ----------
__global__ void detect_dtype(const unsigned short* __restrict__ u, int* __restrict__ flag){
    int bad = 0;
    for (int i = threadIdx.x; i < 4096; i += 256){
        int e = (u[i] >> 7) & 0xFF;
        if (e >= 0x90) bad = 1;
    }
    if (bad) atomicOr(flag, 1);
}

// ---------- device bodies ----------
static __device__ __forceinline__ void tw_body(const void* W, int f32, bf16* WT,
                                               int Kd, int Nd, int nrel, int blk){
    long long idx = (long long)blk * 256 + threadIdx.x;
    long long tot = (long long)nrel * Kd * Nd;
    if (idx >= tot) return;
    int per = Kd * Nd;
    int r = (int)(idx / per);
    int rem = (int)(idx % per);
    int n = rem / Kd, k = rem % Kd;
    float v = ldx(W, (size_t)r*per + (size_t)k*Nd + n, f32);
    WT[idx] = __float2bfloat16(v);
}

static __device__ __forceinline__ void wa1_body(const void* W1, const void* as1, const void* ad1,
                                                int f32, float* wa_s, float* wa_d, int blk){
    int r = blk >> 1;
    int t = (blk & 1)*256 + threadIdx.x;   // 0..511 -> f*4+h
    int f = t >> 2, h = t & 3;
    size_t wb = (size_t)r*128*256 + (size_t)f*256 + h*64;
    size_t ab = (size_t)r*256 + h*64;
    float ss = 0.f, sd = 0.f;
    for (int c = 0; c < 64; c++){
        float w = ldx(W1, wb + c, f32);
        ss += w * ldx(as1, ab + c, f32);
        sd += w * ldx(ad1, ab + c, f32);
    }
    wa_s[r*512 + t] = ss; wa_d[r*512 + t] = sd;
}

static __device__ __forceinline__ void wa2_body(const void* W2, const void* as2, const void* ad2,
                                                int f32, float* wa_s, float* wa_d, int r){
    int f = threadIdx.x;
    size_t wb = (size_t)r*256*64 + (size_t)f*64;
    float ss = 0.f, sd = 0.f;
    for (int c = 0; c < 64; c++){
        float w = ldx(W2, wb + c, f32);
        ss += w * ldx(as2, (size_t)r*64 + c, f32);
        sd += w * ldx(ad2, (size_t)r*64 + c, f32);
    }
    wa_s[r*256 + f] = ss; wa_d[r*256 + f] = sd;
}

static __device__ __forceinline__ void bias_body(const void* b1, const void* b2, int f32,
                                                 float* BIAS1, float* BIAS2, int t){
    const int relA[3] = {3, 0, 1};
    const int relB[3] = {5, 4, 2};
    int c = threadIdx.x;
    BIAS1[t*256 + c] = 0.5f*(ldx(b1, relA[t]*256 + c, f32) + ldx(b1, relB[t]*256 + c, f32));
    if (c < 64)
        BIAS2[t*64 + c] = 0.5f*(ldx(b2, relA[t]*64 + c, f32) + ldx(b2, relB[t]*64 + c, f32));
}

static __device__ void al1_body(const Al1Args& a, int f32, int t, int blk, float (*swa)[512]){
    int N = a.nt[t];
    for (int i = threadIdx.x; i < 2048; i += 256) swa[i >> 9][i & 511] = a.wa[t][i >> 9][i & 511];
    __syncthreads();
    int n = blk * 256 + threadIdx.x;
    if (n >= N) return;
    float s[4][4] = {};
    if (f32){
        const float* xr = (const float*)a.x[t] + (size_t)n*128;
        for (int f = 0; f < 128; f++){
            float v = xr[f];
            #pragma unroll
            for (int j = 0; j < 4; j++){
                s[j][0] += v*swa[j][f*4+0]; s[j][1] += v*swa[j][f*4+1];
                s[j][2] += v*swa[j][f*4+2]; s[j][3] += v*swa[j][f*4+3];
            }
        }
    } else {
        const unsigned short* xr = (const unsigned short*)a.x[t] + (size_t)n*128;
        for (int f0 = 0; f0 < 128; f0 += 8){
            us8v v8 = *(const us8v*)(xr + f0);
            #pragma unroll
            for (int jj = 0; jj < 8; jj++){
                float v = us2f(v8[jj]); int f = f0 + jj;
                #pragma unroll
                for (int j = 0; j < 4; j++){
                    s[j][0] += v*swa[j][f*4+0]; s[j][1] += v*swa[j][f*4+1];
                    s[j][2] += v*swa[j][f*4+2]; s[j][3] += v*swa[j][f*4+3];
                }
            }
        }
    }
    #pragma unroll
    for (int j = 0; j < 4; j++)
        *(float4*)(a.out[t][j] + (size_t)n*4) = make_float4(s[j][0], s[j][1], s[j][2], s[j][3]);
}

static __device__ void al2_body(const Al2Args& a, int t, int blk, float (*swa)[256]){
    int N = a.nt[t];
    for (int i = threadIdx.x; i < 1024; i += 256) swa[i >> 8][i & 255] = a.wa[t][i >> 8][i & 255];
    __syncthreads();
    int n = blk * 256 + threadIdx.x;
    if (n >= N) return;
    const unsigned short* xr = a.x[t] + (size_t)n*256;
    float s0 = 0.f, s1 = 0.f, s2 = 0.f, s3 = 0.f;
    for (int f0 = 0; f0 < 256; f0 += 8){
        us8v v8 = *(const us8v*)(xr + f0);
        #pragma unroll
        for (int jj = 0; jj < 8; jj++){
            float v = us2f(v8[jj]); int f = f0 + jj;
            s0 += v*swa[0][f]; s1 += v*swa[1][f]; s2 += v*swa[2][f]; s3 += v*swa[3][f];
        }
    }
    a.out[t][0][n] = s0; a.out[t][1][n] = s1; a.out[t][2][n] = s2; a.out[t][3][n] = s3;
}

static __device__ void gemm_body(const GemmArgs& ga, int af32, const bf16* WT,
                                 bf16* Cb, int N, int K, int nIdx, int yTot,
                                 unsigned short (*As)[40], unsigned short (*Bs)[40]){
    int y = yTot, r = 0;
    while (r < 5 && y >= ga.nblk[r]){ y -= ga.nblk[r]; r++; }
    int M = ga.M[r];
    int m0 = y * 64, n0 = nIdx * 64;
    const void* A = ga.A[r];
    const unsigned short* WTu = (const unsigned short*)WT + ga.bOff[r];
    bf16* C = Cb + ga.cOff[r];
    int tid = threadIdx.x;
    int w = tid >> 6, lane = tid & 63;
    int quad = lane >> 4, l16 = lane & 15;
    int srow = tid >> 2, skc = (tid & 3) * 8;
    f32x4 acc[4] = {};
    for (int k0 = 0; k0 < K; k0 += 32){
        {
            int gr = m0 + srow;
            us8v av;
            if (gr < M){
                if (af32){
                    const float* ap = (const float*)A + (size_t)gr*K + k0 + skc;
                    #pragma unroll
                    for (int j = 0; j < 8; j++) av[j] = f2bu(ap[j]);
                } else {
                    av = *(const us8v*)((const unsigned short*)A + (size_t)gr*K + k0 + skc);
                }
            } else {
                #pragma unroll
                for (int j = 0; j < 8; j++) av[j] = 0;
            }
            *(us8v*)&As[srow][skc] = av;
        }
        *(us8v*)&Bs[srow][skc] = *(const us8v*)(WTu + (size_t)(n0 + srow)*K + k0 + skc);
        __syncthreads();
        short8 af = *(const short8*)&As[w*16 + l16][quad*8];
        #pragma unroll
        for (int c = 0; c < 4; c++){
            short8 bfv = *(const short8*)&Bs[c*16 + l16][quad*8];
            acc[c] = __builtin_amdgcn_mfma_f32_16x16x32_bf16(af, bfv, acc[c], 0, 0, 0);
        }
        __syncthreads();
    }
    #pragma unroll
    for (int c = 0; c < 4; c++){
        #pragma unroll
        for (int i = 0; i < 4; i++){
            int m = m0 + w*16 + quad*4 + i;
            if (m < M) C[(size_t)m*N + n0 + c*16 + l16] = __float2bfloat16(acc[c][i]);
        }
    }
}

// ---------- P1: transpose + wa + bias + csr_count ----------
__global__ void p1_k(P1Args p, const int* __restrict__ flag){
    int bid = blockIdx.x;
    int f32 = *flag;
    if (bid < p.eTw1){
        tw_body(p.W1, f32, p.W1T, 128, 256, 6, bid);
    } else if (bid < p.eTw2){
        tw_body(p.W2, f32, p.W2T, 256, 64, 6, bid - p.eTw1);
    } else if (bid < p.eWa1){
        wa1_body(p.W1, p.as1, p.ad1, f32, p.WA1S, p.WA1D, bid - p.eTw2);
    } else if (bid < p.eWa2){
        wa2_body(p.W2, p.as2, p.ad2, f32, p.WA2S, p.WA2D, bid - p.eWa1);
    } else if (bid < p.eBias){
        bias_body(p.b1, p.b2, f32, p.BIAS1, p.BIAS2, bid - p.eWa2);
    } else {
        int b = bid - p.eBias, r = 0;
        while (r < 5 && b >= p.nbCnt[r]){ b -= p.nbCnt[r]; r++; }
        int e = b*256 + threadIdx.x;
        if (e < p.ca.ecnt[r]) atomicAdd(&p.CNT[r*OFFSTR + p.ca.dst[r][e]], 1);
    }
}

// ---------- scan (1024 threads, 6 blocks) ----------
__global__ void csr_scan_all(CsrArgs a, const int* __restrict__ cnt, int* __restrict__ off){
    int r = blockIdx.x;
    int N = a.nd[r];
    const int* c = cnt + r*OFFSTR;
    int* o = off + r*OFFSTR;
    __shared__ int wsum[16];
    __shared__ int base;
    int tid = threadIdx.x, lane = tid & 63, wv = tid >> 6;
    if (tid == 0) base = 0;
    __syncthreads();
    for (int c0 = 0; c0 < N; c0 += 1024){
        int i = c0 + tid;
        int x = (i < N) ? c[i] : 0;
        #pragma unroll
        for (int d = 1; d < 64; d <<= 1){
            int y = __shfl_up(x, d, 64);
            if (lane >= d) x += y;
        }
        if (lane == 63) wsum[wv] = x;
        __syncthreads();
        if (tid == 0){
            int s = 0;
            #pragma unroll
            for (int k = 0; k < 16; k++){ s += wsum[k]; wsum[k] = s; }
        }
        __syncthreads();
        int woff = (wv == 0) ? 0 : wsum[wv - 1];
        if (i < N) o[i + 1] = base + woff + x;
        int total = wsum[15];
        __syncthreads();
        if (tid == 0) base += total;
        __syncthreads();
    }
    if (tid == 0) o[0] = 0;
}

// ---------- P2: csr_fill + gemm L1 + al1 ----------
__global__ void p2_k(P2Args p, const int* __restrict__ flag){
    __shared__ __align__(16) char smem[10240];
    int bid = blockIdx.x;
    if (bid < p.eFill){
        int b = bid, r = 0;
        while (r < 5 && b >= p.nbCnt[r]){ b -= p.nbCnt[r]; r++; }
        int e = b*256 + threadIdx.x;
        if (e < p.ca.ecnt[r]){
            int d = p.ca.dst[r][e];
            int pos = atomicAdd(&p.POS[r*OFFSTR + d], 1);
            p.SRCS[p.ca.eoff[r] + p.OFF[r*OFFSTR + d] + pos] = (unsigned short)p.ca.src[r][e];
        }
    } else if (bid < p.eGemm){
        int id = bid - p.eFill;
        int nIdx = id & 3, yTot = id >> 2;
        gemm_body(p.g1, *flag, (const bf16*)nullptr + 0 == nullptr ? (const bf16*)p.g1.A[0] : nullptr, // placeholder removed below
                  nullptr, 0, 0, 0, 0, nullptr, nullptr);
    } else {
        int b = bid - p.eGemm, t = 0;
        while (t < 2 && b >= p.nbAl[t]){ b -= p.nbAl[t]; t++; }
        al1_body(p.a1, *flag, t, b, (float(*)[512])smem);
    }
}
// NOTE: gemm WT pointer must come through args; fix with explicit fields:
struct P2ArgsFix { P2Args p; const bf16* W1T; bf16* HS1; };
__global__ void p2_kf(P2ArgsFix q, const int* __restrict__ flag){
    __shared__ __align__(16) char smem[10240];
    P2Args& p = q.p;
    int bid = blockIdx.x;
    if (bid < p.eFill){
        int b = bid, r = 0;
        while (r < 5 && b >= p.nbCnt[r]){ b -= p.nbCnt[r]; r++; }
        int e = b*256 + threadIdx.x;
        if (e < p.ca.ecnt[r]){
            int d = p.ca.dst[r][e];
            int pos = atomicAdd(&p.POS[r*OFFSTR + d], 1);
            p.SRCS[p.ca.eoff[r] + p.OFF[r*OFFSTR + d] + pos] = (unsigned short)p.ca.src[r][e];
        }
    } else if (bid < p.eGemm){
        int id = bid - p.eFill;
        int nIdx = id & 3, yTot = id >> 2;
        unsigned short (*As)[40] = (unsigned short(*)[40])smem;
        unsigned short (*Bs)[40] = (unsigned short(*)[40])(smem + 5120);
        gemm_body(p.g1, *flag, q.W1T, q.HS1, 256, 128, nIdx, yTot, As, Bs);
    } else {
        int b = bid - p.eGemm, t = 0;
        while (t < 2 && b >= p.nbAl[t]){ b -= p.nbAl[t]; t++; }
        al1_body(p.a1, *flag, t, b, (float(*)[512])smem);
    }
}

// ---------- P3: al2 + gemm L2 ----------
struct P3ArgsFix { P3Args p; const bf16* W2T; bf16* HS2; };
__global__ void p3_kf(P3ArgsFix q){
    __shared__ __align__(16) char smem[10240];
    P3Args& p = q.p;
    int bid = blockIdx.x;
    if (bid < p.eAl2){
        int b = bid, t = 0;
        while (t < 2 && b >= p.nbAl[t]){ b -= p.nbAl[t]; t++; }
        al2_body(p.a2, t, b, (float(*)[256])smem);
    } else {
        int yTot = bid - p.eAl2;
        unsigned short (*As)[40] = (unsigned short(*)[40])smem;
        unsigned short (*Bs)[40] = (unsigned short(*)[40])(smem + 5120);
        gemm_body(p.g2, 0, q.W2T, q.HS2, 64, 256, 0, yTot, As, Bs);
    }
}

// ---------- layer-1 gather: one pass (den folded), 8 edges in flight ----------
__global__ void gat_l1(GatArgs g, const float* __restrict__ BIAS1,
                       unsigned short* __restrict__ X2B){
    int gw = blockIdx.x * 4 + (threadIdx.x >> 6);
    if (gw >= NTOT) return;
    int t, w;
    if (gw < NCIRC){ t = 0; w = gw; }
    else if (gw < NCIRC + NMI){ t = 1; w = gw - NCIRC; }
    else { t = 2; w = gw - NCIRC - NMI; }
    int lane = threadIdx.x & 63;
    int hw = lane >> 5, l32 = lane & 31;
    int h = l32 >> 3;
    float fT[8] = {0.f,0.f,0.f,0.f,0.f,0.f,0.f,0.f};
    #pragma unroll
    for (int a = 0; a < 2; a++){
        const float* als = g.als[t][a];
        const unsigned short* srcs = g.srcs[t][a];
        const unsigned short* Hu = g.hs[t][a];
        float aldv = g.ald[t][a][(size_t)w*4 + h];
        int beg = g.off[t][a][w], end = g.off[t][a][w+1];
        float fa[8] = {0.f,0.f,0.f,0.f,0.f,0.f,0.f,0.f};
        float den = 0.f;
        int i = beg + hw;
        for (; i + 14 < end; i += 16){
            int sv[8]; us8v vv[8]; float ev[8];
            #pragma unroll
            for (int j = 0; j < 8; j++) sv[j] = srcs[i + 2*j];
            #pragma unroll
            for (int j = 0; j < 8; j++) vv[j] = *(const us8v*)(Hu + (size_t)sv[j]*256 + l32*8);
            #pragma unroll
            for (int j = 0; j < 8; j++){
                float xv = als[(size_t)sv[j]*4 + h] + aldv;
                ev[j] = __expf(xv > 0.f ? xv : 0.2f*xv);
                den += ev[j];
            }
            #pragma unroll
            for (int j = 0; j < 8; j++)
                #pragma unroll
                for (int k = 0; k < 8; k++) fa[k] += ev[j]*us2f(vv[j][k]);
        }
        for (; i < end; i += 2){
            int s = srcs[i];
            us8v v = *(const us8v*)(Hu + (size_t)s*256 + l32*8);
            float xv = als[(size_t)s*4 + h] + aldv;
            float e = __expf(xv > 0.f ? xv : 0.2f*xv);
            den += e;
            #pragma unroll
            for (int k = 0; k < 8; k++) fa[k] += e*us2f(v[k]);
        }
        den += __shfl_xor(den, 32, 64);
        float inv = 1.0f / (den + 1e-16f);
        #pragma unroll
        for (int k = 0; k < 8; k++) fT[k] += fa[k]*inv;
    }
    #pragma unroll
    for (int k = 0; k < 8; k++) fT[k] += __shfl_xor(fT[k], 32, 64);
    if (hw == 0){
        const float* bp = BIAS1 + t*256 + l32*8;
        us8v st;
        #pragma unroll
        for (int k = 0; k < 8; k++){
            float v = fT[k]*0.5f + bp[k];
            v = v > 0.f ? v : (__expf(v) - 1.f);
            st[k] = f2bu(v);
        }
        *(us8v*)(X2B + (size_t)gw*256 + l32*8) = st;
    }
}

// ---------- layer-2 gather: one pass, quarter-wave, 8 edges in flight, fused finalize ----------
__global__ void gat_l2(GatArgs g, const float* __restrict__ BIAS2,
                       void* __restrict__ out, const int* __restrict__ flag){
    int gw = blockIdx.x * 4 + (threadIdx.x >> 6);
    if (gw >= NTOT) return;
    int t, w;
    if (gw < NCIRC){ t = 0; w = gw; }
    else if (gw < NCIRC + NMI){ t = 1; w = gw - NCIRC; }
    else { t = 2; w = gw - NCIRC - NMI; }
    int lane = threadIdx.x & 63;
    int qw = lane >> 4, l16 = lane & 15;
    float fT[4] = {0.f,0.f,0.f,0.f};
    #pragma unroll
    for (int a = 0; a < 2; a++){
        const float* als = g.als[t][a];
        const unsigned short* srcs = g.srcs[t][a];
        const unsigned short* Hu = g.hs[t][a];
        float aldv = g.ald[t][a][w];
        int beg = g.off[t][a][w], end = g.off[t][a][w+1];
        float fa[4] = {0.f,0.f,0.f,0.f};
        float den = 0.f;
        int i = beg + qw;
        for (; i + 28 < end; i += 32){
            int sv[8]; ushort4 vv[8]; float ev[8];
            #pragma unroll
            for (int j = 0; j < 8; j++) sv[j] = srcs[i + 4*j];
            #pragma unroll
            for (int j = 0; j < 8; j++) vv[j] = *(const ushort4*)(Hu + (size_t)sv[j]*64 + l16*4);
            #pragma unroll
            for (int j = 0; j < 8; j++){
                float xv = als[sv[j]] + aldv;
                ev[j] = __expf(xv > 0.f ? xv : 0.2f*xv);
                den += ev[j];
            }
            #pragma unroll
            for (int j = 0; j < 8; j++){
                fa[0] += ev[j]*us2f(vv[j].x); fa[1] += ev[j]*us2f(vv[j].y);
                fa[2] += ev[j]*us2f(vv[j].z); fa[3] += ev[j]*us2f(vv[j].w);
            }
        }
        for (; i < end; i += 4){
            int s = srcs[i];
            ushort4 v = *(const ushort4*)(Hu + (size_t)s*64 + l16*4);
            float xv = als[s] + aldv;
            float e = __expf(xv > 0.f ? xv : 0.2f*xv);
            den += e;
            fa[0] += e*us2f(v.x); fa[1] += e*us2f(v.y);
            fa[2] += e*us2f(v.z); fa[3] += e*us2f(v.w);
        }
        den += __shfl_xor(den, 32, 64);
        den += __shfl_xor(den, 16, 64);
        float inv = 1.0f / (den + 1e-16f);
        #pragma unroll
        for (int k = 0; k < 4; k++) fT[k] += fa[k]*inv;
    }
    #pragma unroll
    for (int k = 0; k < 4; k++){
        fT[k] += __shfl_xor(fT[k], 32, 64);
        fT[k] += __shfl_xor(fT[k], 16, 64);
    }
    const float* bp = BIAS2 + t*64 + l16*4;
    float v0 = fT[0]*0.5f + bp[0];
    float v1 = fT[1]*0.5f + bp[1];
    float v2 = fT[2]*0.5f + bp[2];
    float v3 = fT[3]*0.5f + bp[3];
    float ss = v0*v0 + v1*v1 + v2*v2 + v3*v3;
    #pragma unroll
    for (int mk = 8; mk > 0; mk >>= 1) ss += __shfl_xor(ss, mk, 64);
    float nrm = sqrtf(ss);
    nrm = nrm > 1e-12f ? nrm : 1e-12f;
    float inv_n = 1.0f / nrm;
    if (qw == 0){
        size_t base = (size_t)gw*64 + l16*4;
        if (*flag){
            *(float4*)((float*)out + base) = make_float4(v0*inv_n, v1*inv_n, v2*inv_n, v3*inv_n);
        } else {
            ushort4 st;
            st.x = f2bu(v0*inv_n); st.y = f2bu(v1*inv_n);
            st.z = f2bu(v2*inv_n); st.w = f2bu(v3*inv_n);
            *(ushort4*)((unsigned short*)out + base) = st;
        }
    }
}

// ---------- host ----------
extern "C" void kernel_launch(void* const* d_in, const int* in_sizes, int n_in,
                              void* d_out, int out_size, void* d_ws, size_t ws_size,
                              hipStream_t stream){
    const void* x[3] = {d_in[0], d_in[1], d_in[2]};
    const int Nt[3] = {NCIRC, NMI, NDIS};
    const int* ep[6]; int Ecnt[6];
    for (int r = 0; r < 6; r++){ ep[r] = (const int*)d_in[3 + r]; Ecnt[r] = in_sizes[3 + r] / 2; }
    const void* W1  = d_in[9];
    const void* as1 = d_in[10];
    const void* ad1 = d_in[11];
    const void* b1  = d_in[12];
    const void* W2  = d_in[13];
    const void* as2 = d_in[14];
    const void* ad2 = d_in[15];
    const void* b2  = d_in[16];

    const int rs[6] = {0, 1, 0, 1, 2, 2};
    const int rd[6] = {1, 2, 2, 0, 1, 0};
    const int srel[3][2] = {{0, 2}, {1, 3}, {4, 5}};
    const int drel[3][2] = {{3, 5}, {0, 4}, {1, 2}};
    const int accRow[3] = {0, NCIRC, NCIRC + NMI};

    // ---- workspace layout ----
    float* ws    = (float*)d_ws;
    int*   FLAG  = (int*)ws;
    float* WA1S  = ws + 16;
    float* WA1D  = WA1S + 6*512;
    float* WA2S  = WA1D + 6*512;
    float* WA2D  = WA2S + 6*256;
    float* BIAS1 = WA2D + 6*256;
    float* BIAS2 = BIAS1 + 768;
    float* ALB   = BIAS2 + 192;                                 // 1,008,000 floats
    unsigned short* HS1u = (unsigned short*)(ALB + 1008000);    // 32,256,000 ushort
    unsigned short* HS2u = HS1u + 32256000;                     //  8,064,000 ushort
    unsigned short* X2Bu = HS2u + 8064000;                      // 16,128,000 ushort
    bf16*  W1T   = (bf16*)(X2Bu + 16128000);
    bf16*  W2T   = W1T + 6*256*128;
    int*   CNT   = (int*)(W2T + 6*64*256);                      // 6*OFFSTR
    int*   POS   = CNT + 6*OFFSTR;                              // 6*OFFSTR (adjacent for 1 memset)
    int*   OFF   = POS + 6*OFFSTR;                              // 6*OFFSTR
    unsigned short* SRCS = (unsigned short*)(OFF + 6*OFFSTR);   // 2,000,000 ushort

    int eOff[6]; int acc_e = 0;
    for (int r = 0; r < 6; r++){ eOff[r] = acc_e; acc_e += Ecnt[r]; }
    unsigned long long hs1off[6], hs2off[6];
    { unsigned long long o1 = 0, o2 = 0;
      for (int r = 0; r < 6; r++){ hs1off[r] = o1; o1 += (unsigned long long)Nt[rs[r]]*256;
                                   hs2off[r] = o2; o2 += (unsigned long long)Nt[rs[r]]*64; } }
    float *AL1S[6], *AL1D[6], *AL2S[6], *AL2D[6];
    { size_t o = 0;
      for (int r = 0; r < 6; r++){ AL1S[r] = ALB + o; o += (size_t)Nt[rs[r]]*4; }
      for (int r = 0; r < 6; r++){ AL1D[r] = ALB + o; o += (size_t)Nt[rd[r]]*4; }
      size_t o2 = 0;
      for (int r = 0; r < 6; r++){ AL2S[r] = ALB + o2; o2 += (size_t)Nt[rs[r]]; }
      for (int r = 0; r < 6; r++){ AL2D[r] = ALB + o2; o2 += (size_t)Nt[rd[r]]; } }

    CsrArgs ca;
    for (int r = 0; r < 6; r++){
        ca.src[r] = ep[r]; ca.dst[r] = ep[r] + Ecnt[r];
        ca.ecnt[r] = Ecnt[r]; ca.eoff[r] = eOff[r]; ca.nd[r] = Nt[rd[r]];
    }

    // ---- 1-2: memsets ----
    hipMemsetAsync(FLAG, 0, sizeof(int), stream);
    hipMemsetAsync(CNT, 0, (size_t)12*OFFSTR*sizeof(int), stream);
    // ---- 3: dtype ----
    detect_dtype<<<1, 256, 0, stream>>>((const unsigned short*)d_in[0], FLAG);

    // ---- 4: P1 = transpose + wa + bias + count ----
    P1Args p1;
    p1.ca = ca;
    p1.W1 = W1; p1.as1 = as1; p1.ad1 = ad1; p1.W2 = W2; p1.as2 = as2; p1.ad2 = ad2;
    p1.b1 = b1; p1.b2 = b2;
    p1.WA1S = WA1S; p1.WA1D = WA1D; p1.WA2S = WA2S; p1.WA2D = WA2D;
    p1.BIAS1 = BIAS1; p1.BIAS2 = BIAS2;
    p1.W1T = W1T; p1.W2T = W2T; p1.CNT = CNT;
    int nTw1 = cdiv(6LL*128*256, 256), nTw2 = cdiv(6LL*256*64, 256);
    p1.eTw1 = nTw1; p1.eTw2 = nTw1 + nTw2;
    p1.eWa1 = p1.eTw2 + 12; p1.eWa2 = p1.eWa1 + 6; p1.eBias = p1.eWa2 + 3;
    int cntBlk = 0;
    for (int r = 0; r < 6; r++){ p1.nbCnt[r] = cdiv(Ecnt[r], 256); cntBlk += p1.nbCnt[r]; }
    p1_k<<<p1.eBias + cntBlk, 256, 0, stream>>>(p1, FLAG);

    // ---- 5: scan ----
    csr_scan_all<<<6, 1024, 0, stream>>>(ca, CNT, OFF);

    // ---- 6: P2 = fill + gemm L1 + al1 ----
    P2ArgsFix q2;
    q2.p.ca = ca; q2.p.OFF = OFF; q2.p.POS = POS; q2.p.SRCS = SRCS;
    int totBlk1 = 0;
    for (int r = 0; r < 6; r++){
        q2.p.g1.A[r] = x[rs[r]]; q2.p.g1.bOff[r] = (unsigned long long)r*256*128;
        q2.p.g1.cOff[r] = hs1off[r]; q2.p.g1.M[r] = Nt[rs[r]];
        q2.p.g1.nblk[r] = cdiv(Nt[rs[r]], 64); totBlk1 += q2.p.g1.nblk[r];
        q2.p.nbCnt[r] = p1.nbCnt[r];
    }
    for (int t = 0; t < 3; t++){
        q2.p.a1.x[t] = x[t]; q2.p.a1.nt[t] = Nt[t];
        q2.p.nbAl[t] = cdiv(Nt[t], 256);
        for (int j = 0; j < 2; j++){
            q2.p.a1.wa[t][j]   = WA1S + srel[t][j]*512;  q2.p.a1.out[t][j]   = AL1S[srel[t][j]];
            q2.p.a1.wa[t][j+2] = WA1D + drel[t][j]*512;  q2.p.a1.out[t][j+2] = AL1D[drel[t][j]];
        }
    }
    q2.p.eFill = cntBlk; q2.p.eGemm = cntBlk + 4*totBlk1;
    q2.W1T = W1T; q2.HS1 = (bf16*)HS1u;
    int nAl1 = q2.p.nbAl[0] + q2.p.nbAl[1] + q2.p.nbAl[2];
    p2_kf<<<q2.p.eGemm + nAl1, 256, 0, stream>>>(q2, FLAG);

    // ---- 7: gat_l1 ----
    GatArgs gl1;
    for (int t = 0; t < 3; t++)
        for (int a = 0; a < 2; a++){
            int r = drel[t][a];
            gl1.srcs[t][a] = SRCS + eOff[r]; gl1.off[t][a] = OFF + r*OFFSTR;
            gl1.als[t][a] = AL1S[r]; gl1.ald[t][a] = AL1D[r];
            gl1.hs[t][a] = HS1u + hs1off[r];
        }
    gat_l1<<<cdiv(NTOT, 4), 256, 0, stream>>>(gl1, BIAS1, X2Bu);

    // ---- 8: P3 = al2 + gemm L2 ----
    P3ArgsFix q3;
    int totBlk2 = 0;
    for (int r = 0; r < 6; r++){
        q3.p.g2.A[r] = X2Bu + (size_t)accRow[rs[r]]*256;
        q3.p.g2.bOff[r] = (unsigned long long)r*64*256;
        q3.p.g2.cOff[r] = hs2off[r]; q3.p.g2.M[r] = Nt[rs[r]];
        q3.p.g2.nblk[r] = cdiv(Nt[rs[r]], 64); totBlk2 += q3.p.g2.nblk[r];
    }
    for (int t = 0; t < 3; t++){
        q3.p.a2.x[t] = X2Bu + (size_t)accRow[t]*256; q3.p.a2.nt[t] = Nt[t];
        q3.p.nbAl[t] = cdiv(Nt[t], 256);
        for (int j = 0; j < 2; j++){
            q3.p.a2.wa[t][j]   = WA2S + srel[t][j]*256;  q3.p.a2.out[t][j]   = AL2S[srel[t][j]];
            q3.p.a2.wa[t][j+2] = WA2D + drel[t][j]*256;  q3.p.a2.out[t][j+2] = AL2D[drel[t][j]];
        }
    }
    q3.p.eAl2 = q3.p.nbAl[0] + q3.p.nbAl[1] + q3.p.nbAl[2];
    q3.W2T = W2T; q3.HS2 = (bf16*)HS2u;
    p3_kf<<<q3.p.eAl2 + totBlk2, 256, 0, stream>>>(q3);

    // ---- 9: gat_l2 ----
    GatArgs gl2;
    for (int t = 0; t < 3; t++)
        for (int a = 0; a < 2; a++){
            int r = drel[t][a];
            gl2.srcs[t][a] = SRCS + eOff[r]; gl2.off[t][a] = OFF + r*OFFSTR;
            gl2.als[t][a] = AL2S[r]; gl2.ald[t][a] = AL2D[r];
            gl2.hs[t][a] = HS2u + hs2off[r];
        }
    gat_l2<<<cdiv(NTOT, 4), 256, 0, stream>>>(gl2, BIAS2, d_out, FLAG);
}